// Round 2
// baseline (314.892 us; speedup 1.0000x reference)
//
#include <hip/hip_runtime.h>
#include <hip/hip_bf16.h>
#include <hip/hip_fp16.h>

// Problem constants (from reference)
#define NODES 50000
#define NEDGE 800000
#define NE2   850000   // NEDGE + NODES self-loops
#define INDIM 128
#define F1    256      // HEADS*HID
#define HEADS 4
#define HID   64
#define OUTD  64
#define MTILES 3125    // NODES/16

// Bucketed CSR build (no global atomics)
#define NB   196       // buckets = ceil(NODES/256); bucket q covers nodes [q*256, ...)
#define PB   196       // partition blocks
#define EPB  4096      // edges per partition block (196*4096 = 802816 >= NEDGE)
#define TOTH (NB*PB)   // 38416 count-matrix entries

typedef _Float16 f16;
typedef _Float16 f16x8 __attribute__((ext_vector_type(8)));
typedef float    f32x4 __attribute__((ext_vector_type(4)));

// ===== CSR pass 1: per-block LDS bucket histogram (+ W pre-swizzle blocks) ==
__global__ void k_hist(const int* __restrict__ ei, int* __restrict__ blkhist,
                       const float* __restrict__ W1, const float* __restrict__ W2,
                       f16* __restrict__ W1p, f16* __restrict__ W2p)
{
    const int b = blockIdx.x, t = threadIdx.x;
    if (b < PB) {
        __shared__ int h[NB];
        for (int i = t; i < NB; i += 256) h[i] = 0;
        __syncthreads();
        const int e0 = b * EPB;
        const int eend = min(e0 + EPB, NEDGE);
        for (int i = e0 + t; i < eend; i += 256) {
            int d = ei[NEDGE + i];
            atomicAdd(&h[d >> 8], 1);
        }
        __syncthreads();
        // bucket-major, block-minor layout for the global exclusive scan
        for (int i = t; i < NB; i += 256) blkhist[i * PB + b] = h[i];
    } else {
        int idx = (b - PB) * 256 + t;     // < 49152
        if (idx < 32768) {
            int j = idx & 7, l = (idx >> 3) & 63, fi = idx >> 9;
            int kb = fi & 3, ct = fi >> 2;
            int k = kb * 32 + (l >> 4) * 8 + j;
            int col = ct * 16 + (l & 15);
            W1p[idx] = (f16)W1[k * F1 + col];
        } else {
            int i2 = idx - 32768;         // < 16384
            int j = i2 & 7, l = (i2 >> 3) & 63, fi = i2 >> 9;
            int kb = fi & 7, ct = fi >> 3;
            int k = kb * 32 + (l >> 4) * 8 + j;
            int col = ct * 16 + (l & 15);
            W2p[i2] = (f16)W2[k * OUTD + col];
        }
    }
}

// ===== CSR pass 2: single-block exclusive scan of the count matrix =========
// After this, blkhist[q*PB + p] = global staging offset for (bucket q, block p).
// blkhist[q*PB] is the staging start of bucket q.
__global__ void k_scanS(int* __restrict__ blkhist)
{
    const int t = threadIdx.x;
    const int PT = (TOTH + 255) / 256;    // 151 values per thread
    __shared__ int ps[256];
    const int base = t * PT;
    int s = 0;
    for (int k = 0; k < PT; ++k) {
        int idx = base + k;
        if (idx < TOTH) s += blkhist[idx];
    }
    ps[t] = s;
    __syncthreads();
    for (int off = 1; off < 256; off <<= 1) {
        int tv = (t >= off) ? ps[t - off] : 0;
        __syncthreads();
        ps[t] += tv;
        __syncthreads();
    }
    int excl = ps[t] - s;
    for (int k = 0; k < PT; ++k) {
        int idx = base + k;
        if (idx < TOTH) {
            int v = blkhist[idx];
            blkhist[idx] = excl;
            excl += v;
        }
    }
}

// ===== CSR pass 3: deterministic partition into bucket-ordered staging ======
// Packed edge: src (16 bits, NODES<65536) | (dst&255) << 16.
__global__ void k_part(const int* __restrict__ ei, const int* __restrict__ blkhist,
                       unsigned* __restrict__ staged)
{
    const int b = blockIdx.x, t = threadIdx.x;
    __shared__ int cur[NB];
    for (int i = t; i < NB; i += 256) cur[i] = blkhist[i * PB + b];
    __syncthreads();
    const int e0 = b * EPB;
    const int eend = min(e0 + EPB, NEDGE);
    for (int i = e0 + t; i < eend; i += 256) {
        int sN = ei[i];
        int d  = ei[NEDGE + i];
        int pos = atomicAdd(&cur[d >> 8], 1);       // LDS atomic
        staged[pos] = (unsigned)sN | ((unsigned)(d & 255) << 16);
    }
}

// ===== CSR pass 4: per-bucket row_ptr + dense scatter =======================
// Bucket q owns nodes [q*256, q*256+nn), staging range [estart, eend).
// Final CSR base for the bucket = estart + q*256 (one self-loop per prior node).
__global__ void k_bucket(const unsigned* __restrict__ staged,
                         const int* __restrict__ blkhist,
                         int* __restrict__ row_ptr, int* __restrict__ csr_src)
{
    const int q = blockIdx.x, t = threadIdx.x;
    const int estart = blkhist[q * PB];
    const int eend   = (q == NB - 1) ? NEDGE : blkhist[(q + 1) * PB];
    const int nodebase = q * 256;
    const int nn = min(256, NODES - nodebase);
    const int csrbase = estart + nodebase;

    __shared__ int cnt[256];
    __shared__ int sh[256];
    cnt[t] = 0;
    __syncthreads();
    for (int i = estart + t; i < eend; i += 256)
        atomicAdd(&cnt[staged[i] >> 16], 1);
    __syncthreads();
    int v = cnt[t];
    sh[t] = v;
    __syncthreads();
    for (int off = 1; off < 256; off <<= 1) {
        int tv = (t >= off) ? sh[t - off] : 0;
        __syncthreads();
        sh[t] += tv;
        __syncthreads();
    }
    int excl = sh[t] - v;                 // edges before local node t
    if (t < nn) {
        int r = csrbase + excl + t;       // +t = self-loops of prior local nodes
        row_ptr[nodebase + t] = r;
        csr_src[r] = nodebase + t;        // self-loop in slot 0
        cnt[t] = excl + t + 1;            // local cursor (relative to csrbase)
    }
    __syncthreads();
    for (int i = estart + t; i < eend; i += 256) {
        unsigned u = staged[i];
        int pos = atomicAdd(&cnt[u >> 16], 1);   // LDS atomic
        csr_src[csrbase + pos] = (int)(u & 0xFFFFu);
    }
    if (q == NB - 1 && t == 0) row_ptr[NODES] = NE2;
}

// ====== Layer 1 GEMM (MFMA) + fused attention scores =====================
__global__ __launch_bounds__(256) void k_gemm1m(
    const float* __restrict__ x, const f16* __restrict__ W1p,
    const float* __restrict__ as1, const float* __restrict__ ad1,
    f16* __restrict__ xp1h, float* __restrict__ ssrc, float* __restrict__ sdst)
{
    const int wv = threadIdx.x >> 6, lane = threadIdx.x & 63;
    const int l15 = lane & 15, quad = lane >> 4;
    const int rowtile = blockIdx.x * 4 + wv;
    if (rowtile >= MTILES) return;
    const int rowbase = rowtile * 16;

    f16x8 afrag[4];
    const float* xrow = x + (rowbase + l15) * INDIM + quad * 8;
#pragma unroll
    for (int kb = 0; kb < 4; ++kb) {
        float4 u0 = *(const float4*)(xrow + kb * 32);
        float4 u1 = *(const float4*)(xrow + kb * 32 + 4);
        f16x8 a;
        a[0] = (f16)u0.x; a[1] = (f16)u0.y; a[2] = (f16)u0.z; a[3] = (f16)u0.w;
        a[4] = (f16)u1.x; a[5] = (f16)u1.y; a[6] = (f16)u1.z; a[7] = (f16)u1.w;
        afrag[kb] = a;
    }

    const f16x8* Wf = (const f16x8*)W1p;
    f32x4 acc[16];
#pragma unroll
    for (int ct = 0; ct < 16; ++ct) acc[ct] = (f32x4){0.f, 0.f, 0.f, 0.f};
#pragma unroll
    for (int ct = 0; ct < 16; ++ct) {
#pragma unroll
        for (int kb = 0; kb < 4; ++kb) {
            f16x8 b = Wf[(ct * 4 + kb) * 64 + lane];
            acc[ct] = __builtin_amdgcn_mfma_f32_16x16x32_f16(afrag[kb], b, acc[ct], 0, 0, 0);
        }
    }
    // stores: C/D col = ct*16 + l15, row = quad*4 + r
    const int orow = rowbase + quad * 4;
#pragma unroll
    for (int ct = 0; ct < 16; ++ct) {
#pragma unroll
        for (int r = 0; r < 4; ++r)
            xp1h[(orow + r) * F1 + ct * 16 + l15] = (f16)acc[ct][r];
    }
    // fused scores
    float ps[4][4], pd[4][4];
#pragma unroll
    for (int h = 0; h < 4; ++h)
#pragma unroll
        for (int r = 0; r < 4; ++r) { ps[h][r] = 0.f; pd[h][r] = 0.f; }
#pragma unroll
    for (int ct = 0; ct < 16; ++ct) {
        float av = as1[ct * 16 + l15];
        float dv = ad1[ct * 16 + l15];
        int h = ct >> 2;
#pragma unroll
        for (int r = 0; r < 4; ++r) {
            ps[h][r] = fmaf(acc[ct][r], av, ps[h][r]);
            pd[h][r] = fmaf(acc[ct][r], dv, pd[h][r]);
        }
    }
#pragma unroll
    for (int off = 8; off; off >>= 1) {
#pragma unroll
        for (int h = 0; h < 4; ++h)
#pragma unroll
            for (int r = 0; r < 4; ++r) {
                ps[h][r] += __shfl_xor(ps[h][r], off);
                pd[h][r] += __shfl_xor(pd[h][r], off);
            }
    }
    if (l15 == 0) {
#pragma unroll
        for (int r = 0; r < 4; ++r) {
            int row = orow + r;
            float4 vs = {ps[0][r], ps[1][r], ps[2][r], ps[3][r]};
            float4 vd = {pd[0][r], pd[1][r], pd[2][r], pd[3][r]};
            ((float4*)ssrc)[row] = vs;
            ((float4*)sdst)[row] = vd;
        }
    }
}

// ===== Layer 1 fused softmax+aggregate: ONE wave per node =================
__global__ __launch_bounds__(256) void k_agg1(
    const int* __restrict__ row_ptr, const int* __restrict__ csr_src,
    const float* __restrict__ ssrc, const float* __restrict__ sdst,
    const f16* __restrict__ xp1h, const float* __restrict__ bias,
    f16* __restrict__ hbuf)
{
    const int wv = threadIdx.x >> 6, l = threadIdx.x & 63;
    const int n = blockIdx.x * 4 + wv;
    const int eq = l & 15, ph = l >> 4;        // phase-A role
    const int g  = l >> 4, sub = l & 15;       // phase-B role
    const int sel_lo = (sub >> 3) << 4;        // head of unit sub (0/1) -> lane blk
    const int sel_hi = (2 + (sub >> 3)) << 4;  // head of unit sub+16 (2/3)
    const float sd = sdst[n * HEADS + ph];
    const int jbeg = row_ptr[n], jend = row_ptr[n + 1];
    const f16x8* xv = (const f16x8*)xp1h;

    float den = 0.f;
    float alo[8] = {0.f,0.f,0.f,0.f,0.f,0.f,0.f,0.f};
    float ahi[8] = {0.f,0.f,0.f,0.f,0.f,0.f,0.f,0.f};
    for (int base = jbeg; base < jend; base += 16) {
        int c = jend - base; if (c > 16) c = 16;
        int s = 0; float ex = 0.f;
        if (eq < c) {
            s = csr_src[base + eq];
            float e = ssrc[s * HEADS + ph] + sd;
            e = e > 0.f ? e : 0.2f * e;
            ex = __expf(e);
        }
        den += ex;
        int p = 0;
        for (; p + 7 < c; p += 8) {            // 8 edges: groups (p..p+3),(p+4..p+7)
            int ea = p + g, eb = p + 4 + g;
            int   sa  = __shfl(s, ea),          sb  = __shfl(s, eb);
            float aal = __shfl(ex, ea | sel_lo), aah = __shfl(ex, ea | sel_hi);
            float abl = __shfl(ex, eb | sel_lo), abh = __shfl(ex, eb | sel_hi);
            f16x8 va0 = xv[sa * 32 + sub];
            f16x8 va1 = xv[sa * 32 + sub + 16];
            f16x8 vb0 = xv[sb * 32 + sub];
            f16x8 vb1 = xv[sb * 32 + sub + 16];
#pragma unroll
            for (int j = 0; j < 8; ++j) {
                alo[j] = fmaf(aal, (float)va0[j], alo[j]);
                ahi[j] = fmaf(aah, (float)va1[j], ahi[j]);
            }
#pragma unroll
            for (int j = 0; j < 8; ++j) {
                alo[j] = fmaf(abl, (float)vb0[j], alo[j]);
                ahi[j] = fmaf(abh, (float)vb1[j], ahi[j]);
            }
        }
        for (; p < c; p += 4) {                // 4 edges, ex=0 pads
            int ea = p + g;
            int   sa  = __shfl(s, ea);
            float aal = __shfl(ex, ea | sel_lo), aah = __shfl(ex, ea | sel_hi);
            f16x8 va0 = xv[sa * 32 + sub];
            f16x8 va1 = xv[sa * 32 + sub + 16];
#pragma unroll
            for (int j = 0; j < 8; ++j) {
                alo[j] = fmaf(aal, (float)va0[j], alo[j]);
                ahi[j] = fmaf(aah, (float)va1[j], ahi[j]);
            }
        }
    }
    // per-head denominator: reduce within 16-lane groups -> head ph total
#pragma unroll
    for (int off = 8; off; off >>= 1) den += __shfl_xor(den, off);
    const float dl = __shfl(den, sel_lo);
    const float dh = __shfl(den, sel_hi);
    const float rdl = 1.f / (dl + 1e-16f);
    const float rdh = 1.f / (dh + 1e-16f);
    // combine the 4 edge-groups
#pragma unroll
    for (int j = 0; j < 8; ++j) {
        alo[j] += __shfl_xor(alo[j], 16); alo[j] += __shfl_xor(alo[j], 32);
        ahi[j] += __shfl_xor(ahi[j], 16); ahi[j] += __shfl_xor(ahi[j], 32);
    }
    if (g == 0) {
        const float4* b4 = (const float4*)bias;
        float4 bl0 = b4[sub * 2],        bl1 = b4[sub * 2 + 1];
        float4 bh0 = b4[(sub + 16) * 2], bh1 = b4[(sub + 16) * 2 + 1];
        f16x8 olo, ohi;
        float v;
        v = fmaf(alo[0], rdl, bl0.x); olo[0] = (f16)(v > 0.f ? v : 0.f);
        v = fmaf(alo[1], rdl, bl0.y); olo[1] = (f16)(v > 0.f ? v : 0.f);
        v = fmaf(alo[2], rdl, bl0.z); olo[2] = (f16)(v > 0.f ? v : 0.f);
        v = fmaf(alo[3], rdl, bl0.w); olo[3] = (f16)(v > 0.f ? v : 0.f);
        v = fmaf(alo[4], rdl, bl1.x); olo[4] = (f16)(v > 0.f ? v : 0.f);
        v = fmaf(alo[5], rdl, bl1.y); olo[5] = (f16)(v > 0.f ? v : 0.f);
        v = fmaf(alo[6], rdl, bl1.z); olo[6] = (f16)(v > 0.f ? v : 0.f);
        v = fmaf(alo[7], rdl, bl1.w); olo[7] = (f16)(v > 0.f ? v : 0.f);
        v = fmaf(ahi[0], rdh, bh0.x); ohi[0] = (f16)(v > 0.f ? v : 0.f);
        v = fmaf(ahi[1], rdh, bh0.y); ohi[1] = (f16)(v > 0.f ? v : 0.f);
        v = fmaf(ahi[2], rdh, bh0.z); ohi[2] = (f16)(v > 0.f ? v : 0.f);
        v = fmaf(ahi[3], rdh, bh0.w); ohi[3] = (f16)(v > 0.f ? v : 0.f);
        v = fmaf(ahi[4], rdh, bh1.x); ohi[4] = (f16)(v > 0.f ? v : 0.f);
        v = fmaf(ahi[5], rdh, bh1.y); ohi[5] = (f16)(v > 0.f ? v : 0.f);
        v = fmaf(ahi[6], rdh, bh1.z); ohi[6] = (f16)(v > 0.f ? v : 0.f);
        v = fmaf(ahi[7], rdh, bh1.w); ohi[7] = (f16)(v > 0.f ? v : 0.f);
        ((f16x8*)hbuf)[n * 32 + sub] = olo;
        ((f16x8*)hbuf)[n * 32 + sub + 16] = ohi;
    }
}

// ====== Layer 2 GEMM (MFMA) + fused scores ================================
__global__ __launch_bounds__(256) void k_gemm2m(
    const f16* __restrict__ hbuf, const f16* __restrict__ W2p,
    const float* __restrict__ as2, const float* __restrict__ ad2,
    f16* __restrict__ xp2h, float* __restrict__ ssrc, float* __restrict__ sdst)
{
    const int wv = threadIdx.x >> 6, lane = threadIdx.x & 63;
    const int l15 = lane & 15, quad = lane >> 4;
    const int rowtile = blockIdx.x * 4 + wv;
    if (rowtile >= MTILES) return;
    const int rowbase = rowtile * 16;

    const f16x8* Wf = (const f16x8*)W2p;
    f32x4 acc[4];
#pragma unroll
    for (int ct = 0; ct < 4; ++ct) acc[ct] = (f32x4){0.f, 0.f, 0.f, 0.f};
    const f16* hrow = hbuf + (rowbase + l15) * F1 + quad * 8;
#pragma unroll
    for (int kb = 0; kb < 8; ++kb) {
        f16x8 a = *(const f16x8*)(hrow + kb * 32);
#pragma unroll
        for (int ct = 0; ct < 4; ++ct) {
            f16x8 b = Wf[(ct * 8 + kb) * 64 + lane];
            acc[ct] = __builtin_amdgcn_mfma_f32_16x16x32_f16(a, b, acc[ct], 0, 0, 0);
        }
    }
    const int orow = rowbase + quad * 4;
#pragma unroll
    for (int ct = 0; ct < 4; ++ct) {
#pragma unroll
        for (int r = 0; r < 4; ++r)
            xp2h[(orow + r) * OUTD + ct * 16 + l15] = (f16)acc[ct][r];
    }
    float ps[4] = {0.f,0.f,0.f,0.f}, pd[4] = {0.f,0.f,0.f,0.f};
#pragma unroll
    for (int ct = 0; ct < 4; ++ct) {
        float av = as2[ct * 16 + l15];
        float dv = ad2[ct * 16 + l15];
#pragma unroll
        for (int r = 0; r < 4; ++r) {
            ps[r] = fmaf(acc[ct][r], av, ps[r]);
            pd[r] = fmaf(acc[ct][r], dv, pd[r]);
        }
    }
#pragma unroll
    for (int off = 8; off; off >>= 1) {
#pragma unroll
        for (int r = 0; r < 4; ++r) {
            ps[r] += __shfl_xor(ps[r], off);
            pd[r] += __shfl_xor(pd[r], off);
        }
    }
    if (l15 == 0) {
#pragma unroll
        for (int r = 0; r < 4; ++r) {
            ssrc[orow + r] = ps[r];
            sdst[orow + r] = pd[r];
        }
    }
}

// ===== Layer 2 fused softmax+aggregate+bias -> d_out: b128 gather =====
__global__ __launch_bounds__(256) void k_agg2(
    const int* __restrict__ row_ptr, const int* __restrict__ csr_src,
    const float* __restrict__ ssrc, const float* __restrict__ sdst,
    const f16* __restrict__ xp2h, const float* __restrict__ bias,
    float* __restrict__ out)
{
    const int wv = threadIdx.x >> 6, l = threadIdx.x & 63;
    const int n = blockIdx.x * 4 + wv;
    const int grp = l >> 3, sub = l & 7;
    const float sd = sdst[n];
    const int jbeg = row_ptr[n], jend = row_ptr[n + 1];
    const f16x8* xv = (const f16x8*)xp2h;

    float den = 0.f;
    float acc[8] = {0.f,0.f,0.f,0.f,0.f,0.f,0.f,0.f};
    for (int base = jbeg; base < jend; base += 64) {
        int c = jend - base; if (c > 64) c = 64;
        int s = 0; float ex = 0.f;
        if (l < c) {
            s = csr_src[base + l];
            float e = ssrc[s] + sd;
            e = e > 0.f ? e : 0.2f * e;
            ex = __expf(e);
        }
        den += ex;
        int i = 0;
        for (; 8 * (i + 1) < c; i += 2) {
            int ea = 8 * i + grp, eb = 8 * i + 8 + grp;
            int   sa = __shfl(s, ea),  sb = __shfl(s, eb);
            float aa = __shfl(ex, ea), ab = __shfl(ex, eb);
            f16x8 va = xv[sa * 8 + sub];
            f16x8 vb = xv[sb * 8 + sub];
#pragma unroll
            for (int j = 0; j < 8; ++j) acc[j] = fmaf(aa, (float)va[j], acc[j]);
#pragma unroll
            for (int j = 0; j < 8; ++j) acc[j] = fmaf(ab, (float)vb[j], acc[j]);
        }
        for (; 8 * i < c; ++i) {
            int eidx = 8 * i + grp;
            int   se = __shfl(s, eidx);
            float ae = __shfl(ex, eidx);
            f16x8 v = xv[se * 8 + sub];
#pragma unroll
            for (int j = 0; j < 8; ++j) acc[j] = fmaf(ae, (float)v[j], acc[j]);
        }
    }
#pragma unroll
    for (int off = 32; off; off >>= 1) den += __shfl_xor(den, off);
    const float rd = 1.f / (den + 1e-16f);
#pragma unroll
    for (int j = 0; j < 8; ++j) {
        acc[j] += __shfl_xor(acc[j], 8);
        acc[j] += __shfl_xor(acc[j], 16);
        acc[j] += __shfl_xor(acc[j], 32);
    }
    if (grp == 0) {
        const float4* b4 = (const float4*)bias;
        float4 ba = b4[sub * 2], bb = b4[sub * 2 + 1];
        float4 o0, o1;
        o0.x = fmaf(acc[0], rd, ba.x); o0.y = fmaf(acc[1], rd, ba.y);
        o0.z = fmaf(acc[2], rd, ba.z); o0.w = fmaf(acc[3], rd, ba.w);
        o1.x = fmaf(acc[4], rd, bb.x); o1.y = fmaf(acc[5], rd, bb.y);
        o1.z = fmaf(acc[6], rd, bb.z); o1.w = fmaf(acc[7], rd, bb.w);
        float4* ov = (float4*)out + n * 16 + sub * 2;
        ov[0] = o0; ov[1] = o1;
    }
}

extern "C" void kernel_launch(void* const* d_in, const int* in_sizes, int n_in,
                              void* d_out, int out_size, void* d_ws, size_t ws_size,
                              hipStream_t stream)
{
    (void)in_sizes; (void)n_in; (void)out_size; (void)ws_size;
    const float* x   = (const float*)d_in[0];
    const int*   ei  = (const int*)d_in[1];
    const float* W1  = (const float*)d_in[2];
    const float* as1 = (const float*)d_in[3];
    const float* ad1 = (const float*)d_in[4];
    const float* b1  = (const float*)d_in[5];
    const float* W2  = (const float*)d_in[6];
    const float* as2 = (const float*)d_in[7];
    const float* ad2 = (const float*)d_in[8];
    const float* b2  = (const float*)d_in[9];
    float* out = (float*)d_out;

    // workspace layout (~61 MB)
    f16* xp1h    = (f16*)d_ws;                             // N*256 f16 (25.6 MB)
    f16* hbuf    = xp1h + (size_t)NODES * F1;              // N*256 f16 (25.6 MB)
    f16* W1p     = hbuf + (size_t)NODES * F1;              // 32768 f16
    f16* W2p     = W1p + 32768;                            // 16384 f16
    float* ssrc1 = (float*)(W2p + 16384);                  // N*4
    float* sdst1 = ssrc1 + (size_t)NODES * HEADS;          // N*4
    float* ssrc2 = sdst1 + (size_t)NODES * HEADS;          // N
    float* sdst2 = ssrc2 + (size_t)NODES;                  // N
    int* row_ptr = (int*)(sdst2 + (size_t)NODES);          // N+1
    int* blkhist = row_ptr + NODES + 1;                    // NB*PB = 38416
    int* csr_src = blkhist + TOTH;                         // NE2
    unsigned* staged = (unsigned*)(csr_src + NE2);         // NEDGE (3.2 MB)
    f16* xp2h    = xp1h;   // alias: xp1h dead after k_agg1

    // ---- CSR build: bucketed counting sort, zero global atomics ----
    k_hist<<<PB + 192, 256, 0, stream>>>(ei, blkhist, W1, W2, W1p, W2p);
    k_scanS<<<1, 256, 0, stream>>>(blkhist);
    k_part<<<PB, 256, 0, stream>>>(ei, blkhist, staged);
    k_bucket<<<NB, 256, 0, stream>>>(staged, blkhist, row_ptr, csr_src);

    // ---- layer 1 ----
    k_gemm1m<<<(MTILES + 3) / 4, 256, 0, stream>>>(x, W1p, as1, ad1,
                                                   xp1h, ssrc1, sdst1);
    k_agg1<<<NODES / 4, 256, 0, stream>>>(row_ptr, csr_src, ssrc1, sdst1,
                                          xp1h, b1, hbuf);

    // ---- layer 2 ----
    k_gemm2m<<<(MTILES + 3) / 4, 256, 0, stream>>>(hbuf, W2p, as2, ad2,
                                                   xp2h, ssrc2, sdst2);
    k_agg2<<<NODES / 4, 256, 0, stream>>>(row_ptr, csr_src, ssrc2, sdst2,
                                          xp2h, b2, out);
}

// Round 3
// 236.463 us; speedup vs baseline: 1.3317x; 1.3317x over previous
//
#include <hip/hip_runtime.h>
#include <hip/hip_bf16.h>
#include <hip/hip_fp16.h>

// Problem constants (from reference)
#define NODES 50000
#define NEDGE 800000
#define NE2   850000   // NEDGE + NODES self-loops
#define INDIM 128
#define F1    256      // HEADS*HID
#define HEADS 4
#define HID   64
#define OUTD  64
#define MTILES 3125    // NODES/16

// Bucketed CSR build (no global atomics)
#define NB   196       // buckets = ceil(NODES/256); bucket q covers nodes [q*256, ...)
#define PB   196       // partition blocks
#define EPB  4096      // edges per partition block (196*4096 = 802816 >= NEDGE)
#define TOTH (NB*PB)   // 38416 count-matrix entries

typedef _Float16 f16;
typedef _Float16 f16x8 __attribute__((ext_vector_type(8)));
typedef float    f32x4 __attribute__((ext_vector_type(4)));

// ===== CSR pass 1: per-block LDS bucket histogram (+ W pre-swizzle blocks) ==
__global__ void k_hist(const int* __restrict__ ei, int* __restrict__ blkhist,
                       const float* __restrict__ W1, const float* __restrict__ W2,
                       f16* __restrict__ W1p, f16* __restrict__ W2p)
{
    const int b = blockIdx.x, t = threadIdx.x;
    if (b < PB) {
        __shared__ int h[NB];
        for (int i = t; i < NB; i += 256) h[i] = 0;
        __syncthreads();
        const int e0 = b * EPB;
        const int eend = min(e0 + EPB, NEDGE);
        for (int i = e0 + t; i < eend; i += 256) {
            int d = ei[NEDGE + i];
            atomicAdd(&h[d >> 8], 1);
        }
        __syncthreads();
        // row-major [bucket][block] layout
        for (int i = t; i < NB; i += 256) blkhist[i * PB + b] = h[i];
    } else {
        int idx = (b - PB) * 256 + t;     // < 49152
        if (idx < 32768) {
            int j = idx & 7, l = (idx >> 3) & 63, fi = idx >> 9;
            int kb = fi & 3, ct = fi >> 2;
            int k = kb * 32 + (l >> 4) * 8 + j;
            int col = ct * 16 + (l & 15);
            W1p[idx] = (f16)W1[k * F1 + col];
        } else {
            int i2 = idx - 32768;         // < 16384
            int j = i2 & 7, l = (i2 >> 3) & 63, fi = i2 >> 9;
            int kb = fi & 7, ct = fi >> 3;
            int k = kb * 32 + (l >> 4) * 8 + j;
            int col = ct * 16 + (l & 15);
            W2p[i2] = (f16)W2[k * OUTD + col];
        }
    }
}

// ===== CSR pass 2: per-row exclusive scan (196 entries/row, 1 block/row) ====
// blkhist[q][p] -> exclusive-within-row; rowtot[q] = row total (bucket size).
__global__ void k_scanR(int* __restrict__ blkhist, int* __restrict__ rowtot)
{
    __shared__ int sh[256];
    const int q = blockIdx.x, t = threadIdx.x;
    int v = (t < PB) ? blkhist[q * PB + t] : 0;
    sh[t] = v; __syncthreads();
    for (int off = 1; off < 256; off <<= 1) {
        int tv = (t >= off) ? sh[t - off] : 0;
        __syncthreads();
        sh[t] += tv;
        __syncthreads();
    }
    if (t < PB) blkhist[q * PB + t] = sh[t] - v;
    if (t == 255) rowtot[q] = sh[255];
}

// ===== CSR pass 3: deterministic partition into bucket-ordered staging ======
// Bucket start S[q] is recomputed per-block from rowtot (196-entry LDS scan),
// avoiding any serial global scan. Packed edge: src | (dst&255)<<16.
__global__ void k_part(const int* __restrict__ ei, const int* __restrict__ blkhist,
                       const int* __restrict__ rowtot, unsigned* __restrict__ staged)
{
    const int b = blockIdx.x, t = threadIdx.x;
    __shared__ int sS[256];
    __shared__ int cur[NB];
    int v = (t < NB) ? rowtot[t] : 0;
    sS[t] = v; __syncthreads();
    for (int off = 1; off < 256; off <<= 1) {
        int tv = (t >= off) ? sS[t - off] : 0;
        __syncthreads();
        sS[t] += tv;
        __syncthreads();
    }
    if (t < NB) cur[t] = (sS[t] - v) + blkhist[t * PB + b];  // S[q] + rowexcl
    __syncthreads();
    const int e0 = b * EPB;
    const int eend = min(e0 + EPB, NEDGE);
    for (int i = e0 + t; i < eend; i += 256) {
        int sN = ei[i];
        int d  = ei[NEDGE + i];
        int pos = atomicAdd(&cur[d >> 8], 1);       // LDS atomic
        staged[pos] = (unsigned)sN | ((unsigned)(d & 255) << 16);
    }
}

// ===== CSR pass 4: per-bucket row_ptr + dense scatter =======================
// Bucket q owns nodes [q*256, q*256+nn); staging range [S[q], S[q]+rowtot[q]).
// S[q] computed by a 196-entry shfl reduce. Final CSR base = S[q] + q*256.
__global__ void k_bucket(const unsigned* __restrict__ staged,
                         const int* __restrict__ rowtot,
                         int* __restrict__ row_ptr, int* __restrict__ csr_src)
{
    const int q = blockIdx.x, t = threadIdx.x;
    const int wv = t >> 6, lane = t & 63;
    __shared__ int ssum[4];
    __shared__ int cnt[256];
    __shared__ int sh[256];
    int pv = (t < q) ? rowtot[t] : 0;
#pragma unroll
    for (int off = 32; off; off >>= 1) pv += __shfl_xor(pv, off);
    if (lane == 0) ssum[wv] = pv;
    cnt[t] = 0;
    __syncthreads();
    const int estart = ssum[0] + ssum[1] + ssum[2] + ssum[3];
    const int eend   = estart + rowtot[q];
    const int nodebase = q * 256;
    const int nn = min(256, NODES - nodebase);
    const int csrbase = estart + nodebase;

    for (int i = estart + t; i < eend; i += 256)
        atomicAdd(&cnt[staged[i] >> 16], 1);
    __syncthreads();
    int v = cnt[t];
    sh[t] = v;
    __syncthreads();
    for (int off = 1; off < 256; off <<= 1) {
        int tv = (t >= off) ? sh[t - off] : 0;
        __syncthreads();
        sh[t] += tv;
        __syncthreads();
    }
    int excl = sh[t] - v;                 // edges before local node t
    if (t < nn) {
        int r = csrbase + excl + t;       // +t = self-loops of prior local nodes
        row_ptr[nodebase + t] = r;
        csr_src[r] = nodebase + t;        // self-loop in slot 0
        cnt[t] = excl + t + 1;            // local cursor (relative to csrbase)
    }
    __syncthreads();
    for (int i = estart + t; i < eend; i += 256) {
        unsigned u = staged[i];
        int pos = atomicAdd(&cnt[u >> 16], 1);   // LDS atomic
        csr_src[csrbase + pos] = (int)(u & 0xFFFFu);
    }
    if (q == NB - 1 && t == 0) row_ptr[NODES] = NE2;
}

// ====== Layer 1 GEMM (MFMA) + fused attention scores =====================
__global__ __launch_bounds__(256) void k_gemm1m(
    const float* __restrict__ x, const f16* __restrict__ W1p,
    const float* __restrict__ as1, const float* __restrict__ ad1,
    f16* __restrict__ xp1h, float* __restrict__ ssrc, float* __restrict__ sdst)
{
    const int wv = threadIdx.x >> 6, lane = threadIdx.x & 63;
    const int l15 = lane & 15, quad = lane >> 4;
    const int rowtile = blockIdx.x * 4 + wv;
    if (rowtile >= MTILES) return;
    const int rowbase = rowtile * 16;

    f16x8 afrag[4];
    const float* xrow = x + (rowbase + l15) * INDIM + quad * 8;
#pragma unroll
    for (int kb = 0; kb < 4; ++kb) {
        float4 u0 = *(const float4*)(xrow + kb * 32);
        float4 u1 = *(const float4*)(xrow + kb * 32 + 4);
        f16x8 a;
        a[0] = (f16)u0.x; a[1] = (f16)u0.y; a[2] = (f16)u0.z; a[3] = (f16)u0.w;
        a[4] = (f16)u1.x; a[5] = (f16)u1.y; a[6] = (f16)u1.z; a[7] = (f16)u1.w;
        afrag[kb] = a;
    }

    const f16x8* Wf = (const f16x8*)W1p;
    f32x4 acc[16];
#pragma unroll
    for (int ct = 0; ct < 16; ++ct) acc[ct] = (f32x4){0.f, 0.f, 0.f, 0.f};
#pragma unroll
    for (int ct = 0; ct < 16; ++ct) {
#pragma unroll
        for (int kb = 0; kb < 4; ++kb) {
            f16x8 b = Wf[(ct * 4 + kb) * 64 + lane];
            acc[ct] = __builtin_amdgcn_mfma_f32_16x16x32_f16(afrag[kb], b, acc[ct], 0, 0, 0);
        }
    }
    // stores: C/D col = ct*16 + l15, row = quad*4 + r
    const int orow = rowbase + quad * 4;
#pragma unroll
    for (int ct = 0; ct < 16; ++ct) {
#pragma unroll
        for (int r = 0; r < 4; ++r)
            xp1h[(orow + r) * F1 + ct * 16 + l15] = (f16)acc[ct][r];
    }
    // fused scores
    float ps[4][4], pd[4][4];
#pragma unroll
    for (int h = 0; h < 4; ++h)
#pragma unroll
        for (int r = 0; r < 4; ++r) { ps[h][r] = 0.f; pd[h][r] = 0.f; }
#pragma unroll
    for (int ct = 0; ct < 16; ++ct) {
        float av = as1[ct * 16 + l15];
        float dv = ad1[ct * 16 + l15];
        int h = ct >> 2;
#pragma unroll
        for (int r = 0; r < 4; ++r) {
            ps[h][r] = fmaf(acc[ct][r], av, ps[h][r]);
            pd[h][r] = fmaf(acc[ct][r], dv, pd[h][r]);
        }
    }
#pragma unroll
    for (int off = 8; off; off >>= 1) {
#pragma unroll
        for (int h = 0; h < 4; ++h)
#pragma unroll
            for (int r = 0; r < 4; ++r) {
                ps[h][r] += __shfl_xor(ps[h][r], off);
                pd[h][r] += __shfl_xor(pd[h][r], off);
            }
    }
    if (l15 == 0) {
#pragma unroll
        for (int r = 0; r < 4; ++r) {
            int row = orow + r;
            float4 vs = {ps[0][r], ps[1][r], ps[2][r], ps[3][r]};
            float4 vd = {pd[0][r], pd[1][r], pd[2][r], pd[3][r]};
            ((float4*)ssrc)[row] = vs;
            ((float4*)sdst)[row] = vd;
        }
    }
}

// ===== Layer 1 fused softmax+aggregate: ONE wave per node =================
__global__ __launch_bounds__(256) void k_agg1(
    const int* __restrict__ row_ptr, const int* __restrict__ csr_src,
    const float* __restrict__ ssrc, const float* __restrict__ sdst,
    const f16* __restrict__ xp1h, const float* __restrict__ bias,
    f16* __restrict__ hbuf)
{
    const int wv = threadIdx.x >> 6, l = threadIdx.x & 63;
    const int n = blockIdx.x * 4 + wv;
    const int eq = l & 15, ph = l >> 4;        // phase-A role
    const int g  = l >> 4, sub = l & 15;       // phase-B role
    const int sel_lo = (sub >> 3) << 4;        // head of unit sub (0/1) -> lane blk
    const int sel_hi = (2 + (sub >> 3)) << 4;  // head of unit sub+16 (2/3)
    const float sd = sdst[n * HEADS + ph];
    const int jbeg = row_ptr[n], jend = row_ptr[n + 1];
    const f16x8* xv = (const f16x8*)xp1h;

    float den = 0.f;
    float alo[8] = {0.f,0.f,0.f,0.f,0.f,0.f,0.f,0.f};
    float ahi[8] = {0.f,0.f,0.f,0.f,0.f,0.f,0.f,0.f};
    for (int base = jbeg; base < jend; base += 16) {
        int c = jend - base; if (c > 16) c = 16;
        int s = 0; float ex = 0.f;
        if (eq < c) {
            s = csr_src[base + eq];
            float e = ssrc[s * HEADS + ph] + sd;
            e = e > 0.f ? e : 0.2f * e;
            ex = __expf(e);
        }
        den += ex;
        int p = 0;
        for (; p + 7 < c; p += 8) {            // 8 edges: groups (p..p+3),(p+4..p+7)
            int ea = p + g, eb = p + 4 + g;
            int   sa  = __shfl(s, ea),          sb  = __shfl(s, eb);
            float aal = __shfl(ex, ea | sel_lo), aah = __shfl(ex, ea | sel_hi);
            float abl = __shfl(ex, eb | sel_lo), abh = __shfl(ex, eb | sel_hi);
            f16x8 va0 = xv[sa * 32 + sub];
            f16x8 va1 = xv[sa * 32 + sub + 16];
            f16x8 vb0 = xv[sb * 32 + sub];
            f16x8 vb1 = xv[sb * 32 + sub + 16];
#pragma unroll
            for (int j = 0; j < 8; ++j) {
                alo[j] = fmaf(aal, (float)va0[j], alo[j]);
                ahi[j] = fmaf(aah, (float)va1[j], ahi[j]);
            }
#pragma unroll
            for (int j = 0; j < 8; ++j) {
                alo[j] = fmaf(abl, (float)vb0[j], alo[j]);
                ahi[j] = fmaf(abh, (float)vb1[j], ahi[j]);
            }
        }
        for (; p < c; p += 4) {                // 4 edges, ex=0 pads
            int ea = p + g;
            int   sa  = __shfl(s, ea);
            float aal = __shfl(ex, ea | sel_lo), aah = __shfl(ex, ea | sel_hi);
            f16x8 va0 = xv[sa * 32 + sub];
            f16x8 va1 = xv[sa * 32 + sub + 16];
#pragma unroll
            for (int j = 0; j < 8; ++j) {
                alo[j] = fmaf(aal, (float)va0[j], alo[j]);
                ahi[j] = fmaf(aah, (float)va1[j], ahi[j]);
            }
        }
    }
    // per-head denominator: reduce within 16-lane groups -> head ph total
#pragma unroll
    for (int off = 8; off; off >>= 1) den += __shfl_xor(den, off);
    const float dl = __shfl(den, sel_lo);
    const float dh = __shfl(den, sel_hi);
    const float rdl = 1.f / (dl + 1e-16f);
    const float rdh = 1.f / (dh + 1e-16f);
    // combine the 4 edge-groups
#pragma unroll
    for (int j = 0; j < 8; ++j) {
        alo[j] += __shfl_xor(alo[j], 16); alo[j] += __shfl_xor(alo[j], 32);
        ahi[j] += __shfl_xor(ahi[j], 16); ahi[j] += __shfl_xor(ahi[j], 32);
    }
    if (g == 0) {
        const float4* b4 = (const float4*)bias;
        float4 bl0 = b4[sub * 2],        bl1 = b4[sub * 2 + 1];
        float4 bh0 = b4[(sub + 16) * 2], bh1 = b4[(sub + 16) * 2 + 1];
        f16x8 olo, ohi;
        float v;
        v = fmaf(alo[0], rdl, bl0.x); olo[0] = (f16)(v > 0.f ? v : 0.f);
        v = fmaf(alo[1], rdl, bl0.y); olo[1] = (f16)(v > 0.f ? v : 0.f);
        v = fmaf(alo[2], rdl, bl0.z); olo[2] = (f16)(v > 0.f ? v : 0.f);
        v = fmaf(alo[3], rdl, bl0.w); olo[3] = (f16)(v > 0.f ? v : 0.f);
        v = fmaf(alo[4], rdl, bl1.x); olo[4] = (f16)(v > 0.f ? v : 0.f);
        v = fmaf(alo[5], rdl, bl1.y); olo[5] = (f16)(v > 0.f ? v : 0.f);
        v = fmaf(alo[6], rdl, bl1.z); olo[6] = (f16)(v > 0.f ? v : 0.f);
        v = fmaf(alo[7], rdl, bl1.w); olo[7] = (f16)(v > 0.f ? v : 0.f);
        v = fmaf(ahi[0], rdh, bh0.x); ohi[0] = (f16)(v > 0.f ? v : 0.f);
        v = fmaf(ahi[1], rdh, bh0.y); ohi[1] = (f16)(v > 0.f ? v : 0.f);
        v = fmaf(ahi[2], rdh, bh0.z); ohi[2] = (f16)(v > 0.f ? v : 0.f);
        v = fmaf(ahi[3], rdh, bh0.w); ohi[3] = (f16)(v > 0.f ? v : 0.f);
        v = fmaf(ahi[4], rdh, bh1.x); ohi[4] = (f16)(v > 0.f ? v : 0.f);
        v = fmaf(ahi[5], rdh, bh1.y); ohi[5] = (f16)(v > 0.f ? v : 0.f);
        v = fmaf(ahi[6], rdh, bh1.z); ohi[6] = (f16)(v > 0.f ? v : 0.f);
        v = fmaf(ahi[7], rdh, bh1.w); ohi[7] = (f16)(v > 0.f ? v : 0.f);
        ((f16x8*)hbuf)[n * 32 + sub] = olo;
        ((f16x8*)hbuf)[n * 32 + sub + 16] = ohi;
    }
}

// ====== Layer 2 GEMM (MFMA) + fused scores ================================
__global__ __launch_bounds__(256) void k_gemm2m(
    const f16* __restrict__ hbuf, const f16* __restrict__ W2p,
    const float* __restrict__ as2, const float* __restrict__ ad2,
    f16* __restrict__ xp2h, float* __restrict__ ssrc, float* __restrict__ sdst)
{
    const int wv = threadIdx.x >> 6, lane = threadIdx.x & 63;
    const int l15 = lane & 15, quad = lane >> 4;
    const int rowtile = blockIdx.x * 4 + wv;
    if (rowtile >= MTILES) return;
    const int rowbase = rowtile * 16;

    const f16x8* Wf = (const f16x8*)W2p;
    f32x4 acc[4];
#pragma unroll
    for (int ct = 0; ct < 4; ++ct) acc[ct] = (f32x4){0.f, 0.f, 0.f, 0.f};
    const f16* hrow = hbuf + (rowbase + l15) * F1 + quad * 8;
#pragma unroll
    for (int kb = 0; kb < 8; ++kb) {
        f16x8 a = *(const f16x8*)(hrow + kb * 32);
#pragma unroll
        for (int ct = 0; ct < 4; ++ct) {
            f16x8 b = Wf[(ct * 8 + kb) * 64 + lane];
            acc[ct] = __builtin_amdgcn_mfma_f32_16x16x32_f16(a, b, acc[ct], 0, 0, 0);
        }
    }
    const int orow = rowbase + quad * 4;
#pragma unroll
    for (int ct = 0; ct < 4; ++ct) {
#pragma unroll
        for (int r = 0; r < 4; ++r)
            xp2h[(orow + r) * OUTD + ct * 16 + l15] = (f16)acc[ct][r];
    }
    float ps[4] = {0.f,0.f,0.f,0.f}, pd[4] = {0.f,0.f,0.f,0.f};
#pragma unroll
    for (int ct = 0; ct < 4; ++ct) {
        float av = as2[ct * 16 + l15];
        float dv = ad2[ct * 16 + l15];
#pragma unroll
        for (int r = 0; r < 4; ++r) {
            ps[r] = fmaf(acc[ct][r], av, ps[r]);
            pd[r] = fmaf(acc[ct][r], dv, pd[r]);
        }
    }
#pragma unroll
    for (int off = 8; off; off >>= 1) {
#pragma unroll
        for (int r = 0; r < 4; ++r) {
            ps[r] += __shfl_xor(ps[r], off);
            pd[r] += __shfl_xor(pd[r], off);
        }
    }
    if (l15 == 0) {
#pragma unroll
        for (int r = 0; r < 4; ++r) {
            ssrc[orow + r] = ps[r];
            sdst[orow + r] = pd[r];
        }
    }
}

// ===== Layer 2 fused softmax+aggregate+bias -> d_out: b128 gather =====
__global__ __launch_bounds__(256) void k_agg2(
    const int* __restrict__ row_ptr, const int* __restrict__ csr_src,
    const float* __restrict__ ssrc, const float* __restrict__ sdst,
    const f16* __restrict__ xp2h, const float* __restrict__ bias,
    float* __restrict__ out)
{
    const int wv = threadIdx.x >> 6, l = threadIdx.x & 63;
    const int n = blockIdx.x * 4 + wv;
    const int grp = l >> 3, sub = l & 7;
    const float sd = sdst[n];
    const int jbeg = row_ptr[n], jend = row_ptr[n + 1];
    const f16x8* xv = (const f16x8*)xp2h;

    float den = 0.f;
    float acc[8] = {0.f,0.f,0.f,0.f,0.f,0.f,0.f,0.f};
    for (int base = jbeg; base < jend; base += 64) {
        int c = jend - base; if (c > 64) c = 64;
        int s = 0; float ex = 0.f;
        if (l < c) {
            s = csr_src[base + l];
            float e = ssrc[s] + sd;
            e = e > 0.f ? e : 0.2f * e;
            ex = __expf(e);
        }
        den += ex;
        int i = 0;
        for (; 8 * (i + 1) < c; i += 2) {
            int ea = 8 * i + grp, eb = 8 * i + 8 + grp;
            int   sa = __shfl(s, ea),  sb = __shfl(s, eb);
            float aa = __shfl(ex, ea), ab = __shfl(ex, eb);
            f16x8 va = xv[sa * 8 + sub];
            f16x8 vb = xv[sb * 8 + sub];
#pragma unroll
            for (int j = 0; j < 8; ++j) acc[j] = fmaf(aa, (float)va[j], acc[j]);
#pragma unroll
            for (int j = 0; j < 8; ++j) acc[j] = fmaf(ab, (float)vb[j], acc[j]);
        }
        for (; 8 * i < c; ++i) {
            int eidx = 8 * i + grp;
            int   se = __shfl(s, eidx);
            float ae = __shfl(ex, eidx);
            f16x8 v = xv[se * 8 + sub];
#pragma unroll
            for (int j = 0; j < 8; ++j) acc[j] = fmaf(ae, (float)v[j], acc[j]);
        }
    }
#pragma unroll
    for (int off = 32; off; off >>= 1) den += __shfl_xor(den, off);
    const float rd = 1.f / (den + 1e-16f);
#pragma unroll
    for (int j = 0; j < 8; ++j) {
        acc[j] += __shfl_xor(acc[j], 8);
        acc[j] += __shfl_xor(acc[j], 16);
        acc[j] += __shfl_xor(acc[j], 32);
    }
    if (grp == 0) {
        const float4* b4 = (const float4*)bias;
        float4 ba = b4[sub * 2], bb = b4[sub * 2 + 1];
        float4 o0, o1;
        o0.x = fmaf(acc[0], rd, ba.x); o0.y = fmaf(acc[1], rd, ba.y);
        o0.z = fmaf(acc[2], rd, ba.z); o0.w = fmaf(acc[3], rd, ba.w);
        o1.x = fmaf(acc[4], rd, bb.x); o1.y = fmaf(acc[5], rd, bb.y);
        o1.z = fmaf(acc[6], rd, bb.z); o1.w = fmaf(acc[7], rd, bb.w);
        float4* ov = (float4*)out + n * 16 + sub * 2;
        ov[0] = o0; ov[1] = o1;
    }
}

extern "C" void kernel_launch(void* const* d_in, const int* in_sizes, int n_in,
                              void* d_out, int out_size, void* d_ws, size_t ws_size,
                              hipStream_t stream)
{
    (void)in_sizes; (void)n_in; (void)out_size; (void)ws_size;
    const float* x   = (const float*)d_in[0];
    const int*   ei  = (const int*)d_in[1];
    const float* W1  = (const float*)d_in[2];
    const float* as1 = (const float*)d_in[3];
    const float* ad1 = (const float*)d_in[4];
    const float* b1  = (const float*)d_in[5];
    const float* W2  = (const float*)d_in[6];
    const float* as2 = (const float*)d_in[7];
    const float* ad2 = (const float*)d_in[8];
    const float* b2  = (const float*)d_in[9];
    float* out = (float*)d_out;

    // workspace layout (~61 MB)
    f16* xp1h    = (f16*)d_ws;                             // N*256 f16 (25.6 MB)
    f16* hbuf    = xp1h + (size_t)NODES * F1;              // N*256 f16 (25.6 MB)
    f16* W1p     = hbuf + (size_t)NODES * F1;              // 32768 f16
    f16* W2p     = W1p + 32768;                            // 16384 f16
    float* ssrc1 = (float*)(W2p + 16384);                  // N*4
    float* sdst1 = ssrc1 + (size_t)NODES * HEADS;          // N*4
    float* ssrc2 = sdst1 + (size_t)NODES * HEADS;          // N
    float* sdst2 = ssrc2 + (size_t)NODES;                  // N
    int* row_ptr = (int*)(sdst2 + (size_t)NODES);          // N+1
    int* blkhist = row_ptr + NODES + 1;                    // NB*PB = 38416
    int* rowtot  = blkhist + TOTH;                         // NB
    int* csr_src = rowtot + NB;                            // NE2
    unsigned* staged = (unsigned*)(csr_src + NE2);         // NEDGE (3.2 MB)
    f16* xp2h    = xp1h;   // alias: xp1h dead after k_agg1

    // ---- CSR build: bucketed counting sort, zero global atomics ----
    k_hist<<<PB + 192, 256, 0, stream>>>(ei, blkhist, W1, W2, W1p, W2p);
    k_scanR<<<NB, 256, 0, stream>>>(blkhist, rowtot);
    k_part<<<PB, 256, 0, stream>>>(ei, blkhist, rowtot, staged);
    k_bucket<<<NB, 256, 0, stream>>>(staged, rowtot, row_ptr, csr_src);

    // ---- layer 1 ----
    k_gemm1m<<<(MTILES + 3) / 4, 256, 0, stream>>>(x, W1p, as1, ad1,
                                                   xp1h, ssrc1, sdst1);
    k_agg1<<<NODES / 4, 256, 0, stream>>>(row_ptr, csr_src, ssrc1, sdst1,
                                          xp1h, b1, hbuf);

    // ---- layer 2 ----
    k_gemm2m<<<(MTILES + 3) / 4, 256, 0, stream>>>(hbuf, W2p, as2, ad2,
                                                   xp2h, ssrc2, sdst2);
    k_agg2<<<NODES / 4, 256, 0, stream>>>(row_ptr, csr_src, ssrc2, sdst2,
                                          xp2h, b2, out);
}

// Round 4
// 228.404 us; speedup vs baseline: 1.3787x; 1.0353x over previous
//
#include <hip/hip_runtime.h>
#include <hip/hip_bf16.h>
#include <hip/hip_fp16.h>

// Problem constants (from reference)
#define NODES 50000
#define NEDGE 800000
#define NE2   850000   // NEDGE + NODES self-loops
#define INDIM 128
#define F1    256      // HEADS*HID
#define HEADS 4
#define HID   64
#define OUTD  64
#define MTILES 3125    // NODES/16

// Bucketed CSR build (no global atomics)
#define NB   196       // buckets = ceil(NODES/256); bucket q covers nodes [q*256, ...)
#define PB   196       // partition blocks
#define EPB  4096      // edges per partition block (196*4096 = 802816 >= NEDGE)
#define CAP  6144      // per-bucket LDS sort capacity (mean 4082, sigma 64 -> safe)
#define G1B  782       // ceil(MTILES/4) gemm1 blocks in fused k_bg

typedef _Float16 f16;
typedef _Float16 f16x8 __attribute__((ext_vector_type(8)));
typedef float    f32x4 __attribute__((ext_vector_type(4)));

// ===== CSR pass 1: per-block LDS bucket histogram (+ W pre-swizzle blocks) ==
__global__ void k_hist(const int* __restrict__ ei, int* __restrict__ blkhist,
                       const float* __restrict__ W1, const float* __restrict__ W2,
                       f16* __restrict__ W1p, f16* __restrict__ W2p)
{
    const int b = blockIdx.x, t = threadIdx.x;
    if (b < PB) {
        __shared__ int h[NB];
        for (int i = t; i < NB; i += 256) h[i] = 0;
        __syncthreads();
        const int e0 = b * EPB;
        const int eend = min(e0 + EPB, NEDGE);
        for (int i = e0 + t; i < eend; i += 256) {
            int d = ei[NEDGE + i];
            atomicAdd(&h[d >> 8], 1);
        }
        __syncthreads();
        // row-major [bucket][block] layout
        for (int i = t; i < NB; i += 256) blkhist[i * PB + b] = h[i];
    } else {
        int idx = (b - PB) * 256 + t;     // < 49152
        if (idx < 32768) {
            int j = idx & 7, l = (idx >> 3) & 63, fi = idx >> 9;
            int kb = fi & 3, ct = fi >> 2;
            int k = kb * 32 + (l >> 4) * 8 + j;
            int col = ct * 16 + (l & 15);
            W1p[idx] = (f16)W1[k * F1 + col];
        } else {
            int i2 = idx - 32768;         // < 16384
            int j = i2 & 7, l = (i2 >> 3) & 63, fi = i2 >> 9;
            int kb = fi & 7, ct = fi >> 3;
            int k = kb * 32 + (l >> 4) * 8 + j;
            int col = ct * 16 + (l & 15);
            W2p[i2] = (f16)W2[k * OUTD + col];
        }
    }
}

// ===== CSR pass 2: per-row exclusive scan (196 entries/row, 1 block/row) ====
__global__ void k_scanR(int* __restrict__ blkhist, int* __restrict__ rowtot)
{
    __shared__ int sh[256];
    const int q = blockIdx.x, t = threadIdx.x;
    int v = (t < PB) ? blkhist[q * PB + t] : 0;
    sh[t] = v; __syncthreads();
    for (int off = 1; off < 256; off <<= 1) {
        int tv = (t >= off) ? sh[t - off] : 0;
        __syncthreads();
        sh[t] += tv;
        __syncthreads();
    }
    if (t < PB) blkhist[q * PB + t] = sh[t] - v;
    if (t == 255) rowtot[q] = sh[255];
}

// ===== CSR pass 3: deterministic partition into bucket-ordered staging ======
__global__ void k_part(const int* __restrict__ ei, const int* __restrict__ blkhist,
                       const int* __restrict__ rowtot, unsigned* __restrict__ staged)
{
    const int b = blockIdx.x, t = threadIdx.x;
    __shared__ int sS[256];
    __shared__ int cur[NB];
    int v = (t < NB) ? rowtot[t] : 0;
    sS[t] = v; __syncthreads();
    for (int off = 1; off < 256; off <<= 1) {
        int tv = (t >= off) ? sS[t - off] : 0;
        __syncthreads();
        sS[t] += tv;
        __syncthreads();
    }
    if (t < NB) cur[t] = (sS[t] - v) + blkhist[t * PB + b];  // S[q] + rowexcl
    __syncthreads();
    const int e0 = b * EPB;
    const int eend = min(e0 + EPB, NEDGE);
    for (int i = e0 + t; i < eend; i += 256) {
        int sN = ei[i];
        int d  = ei[NEDGE + i];
        int pos = atomicAdd(&cur[d >> 8], 1);       // LDS atomic
        staged[pos] = (unsigned)sN | ((unsigned)(d & 255) << 16);
    }
}

// ===== FUSED pass 4 + layer-1 GEMM =========================================
// Blocks [0,NB): per-bucket src-sort + row_ptr + dense scatter.
// Blocks [NB,NB+G1B): MFMA GEMM xp1h = x@W1 (+ fused scores).
// Independent: bucket needs staged (k_part); gemm needs W1p (k_hist).
// Bucket blocks first so their latency-bound work overlaps the MFMA flood.
__global__ __launch_bounds__(256) void k_bg(
    const unsigned* __restrict__ staged, const int* __restrict__ rowtot,
    int* __restrict__ row_ptr, int* __restrict__ csr_src,
    const float* __restrict__ x, const f16* __restrict__ W1p,
    const float* __restrict__ as1, const float* __restrict__ ad1,
    f16* __restrict__ xp1h, float* __restrict__ ssrc, float* __restrict__ sdst)
{
    if (blockIdx.x < NB) {
        __shared__ unsigned sorted2[CAP];   // 24 KB
        __shared__ int bin[256];
        __shared__ int cnt[256];
        __shared__ int sh[256];
        __shared__ int ssum[4];
        const int q = blockIdx.x, t = threadIdx.x;
        const int wv = t >> 6, lane = t & 63;
        int pv = (t < q) ? rowtot[t] : 0;
#pragma unroll
        for (int off = 32; off; off >>= 1) pv += __shfl_xor(pv, off);
        if (lane == 0) ssum[wv] = pv;
        cnt[t] = 0; bin[t] = 0;
        __syncthreads();
        const int estart = ssum[0] + ssum[1] + ssum[2] + ssum[3];
        const int m = rowtot[q];            // bucket edge count
        const int nodebase = q * 256;
        const int nn = min(256, NODES - nodebase);
        const int csrbase = estart + nodebase;

        const bool dosort = (m <= CAP);
        if (dosort) {
            // --- coarse src-sort (key = src>>8): count, scan, scatter to LDS ---
            for (int i = t; i < m; i += 256)
                atomicAdd(&bin[(staged[estart + i] & 0xFFFFu) >> 8], 1);
            __syncthreads();
            int bv = bin[t];
            sh[t] = bv;
            __syncthreads();
            for (int off = 1; off < 256; off <<= 1) {
                int tv = (t >= off) ? sh[t - off] : 0;
                __syncthreads();
                sh[t] += tv;
                __syncthreads();
            }
            bin[t] = sh[t] - bv;            // exclusive offsets -> cursors
            __syncthreads();
            for (int i = t; i < m; i += 256) {
                unsigned u = staged[estart + i];
                int p = atomicAdd(&bin[(u & 0xFFFFu) >> 8], 1);
                sorted2[p] = u;
            }
            __syncthreads();
        }

        // --- per-dst count ---
        if (dosort) {
            for (int i = t; i < m; i += 256)
                atomicAdd(&cnt[sorted2[i] >> 16], 1);
        } else {
            for (int i = t; i < m; i += 256)
                atomicAdd(&cnt[staged[estart + i] >> 16], 1);
        }
        __syncthreads();
        int v = cnt[t];
        sh[t] = v;
        __syncthreads();
        for (int off = 1; off < 256; off <<= 1) {
            int tv = (t >= off) ? sh[t - off] : 0;
            __syncthreads();
            sh[t] += tv;
            __syncthreads();
        }
        int excl = sh[t] - v;               // edges before local node t
        __syncthreads();
        if (t < nn) {
            int r = csrbase + excl + t;     // +t = self-loops of prior local nodes
            row_ptr[nodebase + t] = r;
            csr_src[r] = nodebase + t;      // self-loop in slot 0
            cnt[t] = excl + t + 1;          // local cursor (relative to csrbase)
        }
        __syncthreads();
        if (dosort) {
            for (int i = t; i < m; i += 256) {
                unsigned u = sorted2[i];
                int pos = atomicAdd(&cnt[u >> 16], 1);
                csr_src[csrbase + pos] = (int)(u & 0xFFFFu);
            }
        } else {
            for (int i = t; i < m; i += 256) {
                unsigned u = staged[estart + i];
                int pos = atomicAdd(&cnt[u >> 16], 1);
                csr_src[csrbase + pos] = (int)(u & 0xFFFFu);
            }
        }
        if (q == NB - 1 && t == 0) row_ptr[NODES] = NE2;
        return;
    }

    // ---- gemm1 path ----
    const int wv = threadIdx.x >> 6, lane = threadIdx.x & 63;
    const int l15 = lane & 15, quad = lane >> 4;
    const int rowtile = (blockIdx.x - NB) * 4 + wv;
    if (rowtile >= MTILES) return;
    const int rowbase = rowtile * 16;

    f16x8 afrag[4];
    const float* xrow = x + (rowbase + l15) * INDIM + quad * 8;
#pragma unroll
    for (int kb = 0; kb < 4; ++kb) {
        float4 u0 = *(const float4*)(xrow + kb * 32);
        float4 u1 = *(const float4*)(xrow + kb * 32 + 4);
        f16x8 a;
        a[0] = (f16)u0.x; a[1] = (f16)u0.y; a[2] = (f16)u0.z; a[3] = (f16)u0.w;
        a[4] = (f16)u1.x; a[5] = (f16)u1.y; a[6] = (f16)u1.z; a[7] = (f16)u1.w;
        afrag[kb] = a;
    }

    const f16x8* Wf = (const f16x8*)W1p;
    f32x4 acc[16];
#pragma unroll
    for (int ct = 0; ct < 16; ++ct) acc[ct] = (f32x4){0.f, 0.f, 0.f, 0.f};
#pragma unroll
    for (int ct = 0; ct < 16; ++ct) {
#pragma unroll
        for (int kb = 0; kb < 4; ++kb) {
            f16x8 b = Wf[(ct * 4 + kb) * 64 + lane];
            acc[ct] = __builtin_amdgcn_mfma_f32_16x16x32_f16(afrag[kb], b, acc[ct], 0, 0, 0);
        }
    }
    const int orow = rowbase + quad * 4;
#pragma unroll
    for (int ct = 0; ct < 16; ++ct) {
#pragma unroll
        for (int r = 0; r < 4; ++r)
            xp1h[(orow + r) * F1 + ct * 16 + l15] = (f16)acc[ct][r];
    }
    float ps[4][4], pd[4][4];
#pragma unroll
    for (int h = 0; h < 4; ++h)
#pragma unroll
        for (int r = 0; r < 4; ++r) { ps[h][r] = 0.f; pd[h][r] = 0.f; }
#pragma unroll
    for (int ct = 0; ct < 16; ++ct) {
        float av = as1[ct * 16 + l15];
        float dv = ad1[ct * 16 + l15];
        int h = ct >> 2;
#pragma unroll
        for (int r = 0; r < 4; ++r) {
            ps[h][r] = fmaf(acc[ct][r], av, ps[h][r]);
            pd[h][r] = fmaf(acc[ct][r], dv, pd[h][r]);
        }
    }
#pragma unroll
    for (int off = 8; off; off >>= 1) {
#pragma unroll
        for (int h = 0; h < 4; ++h)
#pragma unroll
            for (int r = 0; r < 4; ++r) {
                ps[h][r] += __shfl_xor(ps[h][r], off);
                pd[h][r] += __shfl_xor(pd[h][r], off);
            }
    }
    if (l15 == 0) {
#pragma unroll
        for (int r = 0; r < 4; ++r) {
            int row = orow + r;
            float4 vs = {ps[0][r], ps[1][r], ps[2][r], ps[3][r]};
            float4 vd = {pd[0][r], pd[1][r], pd[2][r], pd[3][r]};
            ((float4*)ssrc)[row] = vs;
            ((float4*)sdst)[row] = vd;
        }
    }
}

// ===== Layer 1 fused softmax+aggregate: ONE wave per node =================
__global__ __launch_bounds__(256) void k_agg1(
    const int* __restrict__ row_ptr, const int* __restrict__ csr_src,
    const float* __restrict__ ssrc, const float* __restrict__ sdst,
    const f16* __restrict__ xp1h, const float* __restrict__ bias,
    f16* __restrict__ hbuf)
{
    const int wv = threadIdx.x >> 6, l = threadIdx.x & 63;
    const int n = blockIdx.x * 4 + wv;
    const int eq = l & 15, ph = l >> 4;        // phase-A role
    const int g  = l >> 4, sub = l & 15;       // phase-B role
    const int sel_lo = (sub >> 3) << 4;        // head of unit sub (0/1) -> lane blk
    const int sel_hi = (2 + (sub >> 3)) << 4;  // head of unit sub+16 (2/3)
    const float sd = sdst[n * HEADS + ph];
    const int jbeg = row_ptr[n], jend = row_ptr[n + 1];
    const f16x8* xv = (const f16x8*)xp1h;

    float den = 0.f;
    float alo[8] = {0.f,0.f,0.f,0.f,0.f,0.f,0.f,0.f};
    float ahi[8] = {0.f,0.f,0.f,0.f,0.f,0.f,0.f,0.f};
    for (int base = jbeg; base < jend; base += 16) {
        int c = jend - base; if (c > 16) c = 16;
        int s = 0; float ex = 0.f;
        if (eq < c) {
            s = csr_src[base + eq];
            float e = ssrc[s * HEADS + ph] + sd;
            e = e > 0.f ? e : 0.2f * e;
            ex = __expf(e);
        }
        den += ex;
        int p = 0;
        for (; p + 7 < c; p += 8) {            // 8 edges: groups (p..p+3),(p+4..p+7)
            int ea = p + g, eb = p + 4 + g;
            int   sa  = __shfl(s, ea),          sb  = __shfl(s, eb);
            float aal = __shfl(ex, ea | sel_lo), aah = __shfl(ex, ea | sel_hi);
            float abl = __shfl(ex, eb | sel_lo), abh = __shfl(ex, eb | sel_hi);
            f16x8 va0 = xv[sa * 32 + sub];
            f16x8 va1 = xv[sa * 32 + sub + 16];
            f16x8 vb0 = xv[sb * 32 + sub];
            f16x8 vb1 = xv[sb * 32 + sub + 16];
#pragma unroll
            for (int j = 0; j < 8; ++j) {
                alo[j] = fmaf(aal, (float)va0[j], alo[j]);
                ahi[j] = fmaf(aah, (float)va1[j], ahi[j]);
            }
#pragma unroll
            for (int j = 0; j < 8; ++j) {
                alo[j] = fmaf(abl, (float)vb0[j], alo[j]);
                ahi[j] = fmaf(abh, (float)vb1[j], ahi[j]);
            }
        }
        for (; p < c; p += 4) {                // 4 edges, ex=0 pads
            int ea = p + g;
            int   sa  = __shfl(s, ea);
            float aal = __shfl(ex, ea | sel_lo), aah = __shfl(ex, ea | sel_hi);
            f16x8 va0 = xv[sa * 32 + sub];
            f16x8 va1 = xv[sa * 32 + sub + 16];
#pragma unroll
            for (int j = 0; j < 8; ++j) {
                alo[j] = fmaf(aal, (float)va0[j], alo[j]);
                ahi[j] = fmaf(aah, (float)va1[j], ahi[j]);
            }
        }
    }
#pragma unroll
    for (int off = 8; off; off >>= 1) den += __shfl_xor(den, off);
    const float dl = __shfl(den, sel_lo);
    const float dh = __shfl(den, sel_hi);
    const float rdl = 1.f / (dl + 1e-16f);
    const float rdh = 1.f / (dh + 1e-16f);
#pragma unroll
    for (int j = 0; j < 8; ++j) {
        alo[j] += __shfl_xor(alo[j], 16); alo[j] += __shfl_xor(alo[j], 32);
        ahi[j] += __shfl_xor(ahi[j], 16); ahi[j] += __shfl_xor(ahi[j], 32);
    }
    if (g == 0) {
        const float4* b4 = (const float4*)bias;
        float4 bl0 = b4[sub * 2],        bl1 = b4[sub * 2 + 1];
        float4 bh0 = b4[(sub + 16) * 2], bh1 = b4[(sub + 16) * 2 + 1];
        f16x8 olo, ohi;
        float v;
        v = fmaf(alo[0], rdl, bl0.x); olo[0] = (f16)(v > 0.f ? v : 0.f);
        v = fmaf(alo[1], rdl, bl0.y); olo[1] = (f16)(v > 0.f ? v : 0.f);
        v = fmaf(alo[2], rdl, bl0.z); olo[2] = (f16)(v > 0.f ? v : 0.f);
        v = fmaf(alo[3], rdl, bl0.w); olo[3] = (f16)(v > 0.f ? v : 0.f);
        v = fmaf(alo[4], rdl, bl1.x); olo[4] = (f16)(v > 0.f ? v : 0.f);
        v = fmaf(alo[5], rdl, bl1.y); olo[5] = (f16)(v > 0.f ? v : 0.f);
        v = fmaf(alo[6], rdl, bl1.z); olo[6] = (f16)(v > 0.f ? v : 0.f);
        v = fmaf(alo[7], rdl, bl1.w); olo[7] = (f16)(v > 0.f ? v : 0.f);
        v = fmaf(ahi[0], rdh, bh0.x); ohi[0] = (f16)(v > 0.f ? v : 0.f);
        v = fmaf(ahi[1], rdh, bh0.y); ohi[1] = (f16)(v > 0.f ? v : 0.f);
        v = fmaf(ahi[2], rdh, bh0.z); ohi[2] = (f16)(v > 0.f ? v : 0.f);
        v = fmaf(ahi[3], rdh, bh0.w); ohi[3] = (f16)(v > 0.f ? v : 0.f);
        v = fmaf(ahi[4], rdh, bh1.x); ohi[4] = (f16)(v > 0.f ? v : 0.f);
        v = fmaf(ahi[5], rdh, bh1.y); ohi[5] = (f16)(v > 0.f ? v : 0.f);
        v = fmaf(ahi[6], rdh, bh1.z); ohi[6] = (f16)(v > 0.f ? v : 0.f);
        v = fmaf(ahi[7], rdh, bh1.w); ohi[7] = (f16)(v > 0.f ? v : 0.f);
        ((f16x8*)hbuf)[n * 32 + sub] = olo;
        ((f16x8*)hbuf)[n * 32 + sub + 16] = ohi;
    }
}

// ====== Layer 2 GEMM (MFMA) + fused scores ================================
__global__ __launch_bounds__(256) void k_gemm2m(
    const f16* __restrict__ hbuf, const f16* __restrict__ W2p,
    const float* __restrict__ as2, const float* __restrict__ ad2,
    f16* __restrict__ xp2h, float* __restrict__ ssrc, float* __restrict__ sdst)
{
    const int wv = threadIdx.x >> 6, lane = threadIdx.x & 63;
    const int l15 = lane & 15, quad = lane >> 4;
    const int rowtile = blockIdx.x * 4 + wv;
    if (rowtile >= MTILES) return;
    const int rowbase = rowtile * 16;

    const f16x8* Wf = (const f16x8*)W2p;
    f32x4 acc[4];
#pragma unroll
    for (int ct = 0; ct < 4; ++ct) acc[ct] = (f32x4){0.f, 0.f, 0.f, 0.f};
    const f16* hrow = hbuf + (rowbase + l15) * F1 + quad * 8;
#pragma unroll
    for (int kb = 0; kb < 8; ++kb) {
        f16x8 a = *(const f16x8*)(hrow + kb * 32);
#pragma unroll
        for (int ct = 0; ct < 4; ++ct) {
            f16x8 b = Wf[(ct * 8 + kb) * 64 + lane];
            acc[ct] = __builtin_amdgcn_mfma_f32_16x16x32_f16(a, b, acc[ct], 0, 0, 0);
        }
    }
    const int orow = rowbase + quad * 4;
#pragma unroll
    for (int ct = 0; ct < 4; ++ct) {
#pragma unroll
        for (int r = 0; r < 4; ++r)
            xp2h[(orow + r) * OUTD + ct * 16 + l15] = (f16)acc[ct][r];
    }
    float ps[4] = {0.f,0.f,0.f,0.f}, pd[4] = {0.f,0.f,0.f,0.f};
#pragma unroll
    for (int ct = 0; ct < 4; ++ct) {
        float av = as2[ct * 16 + l15];
        float dv = ad2[ct * 16 + l15];
#pragma unroll
        for (int r = 0; r < 4; ++r) {
            ps[r] = fmaf(acc[ct][r], av, ps[r]);
            pd[r] = fmaf(acc[ct][r], dv, pd[r]);
        }
    }
#pragma unroll
    for (int off = 8; off; off >>= 1) {
#pragma unroll
        for (int r = 0; r < 4; ++r) {
            ps[r] += __shfl_xor(ps[r], off);
            pd[r] += __shfl_xor(pd[r], off);
        }
    }
    if (l15 == 0) {
#pragma unroll
        for (int r = 0; r < 4; ++r) {
            ssrc[orow + r] = ps[r];
            sdst[orow + r] = pd[r];
        }
    }
}

// ===== Layer 2 fused softmax+aggregate+bias -> d_out: b128 gather =====
__global__ __launch_bounds__(256) void k_agg2(
    const int* __restrict__ row_ptr, const int* __restrict__ csr_src,
    const float* __restrict__ ssrc, const float* __restrict__ sdst,
    const f16* __restrict__ xp2h, const float* __restrict__ bias,
    float* __restrict__ out)
{
    const int wv = threadIdx.x >> 6, l = threadIdx.x & 63;
    const int n = blockIdx.x * 4 + wv;
    const int grp = l >> 3, sub = l & 7;
    const float sd = sdst[n];
    const int jbeg = row_ptr[n], jend = row_ptr[n + 1];
    const f16x8* xv = (const f16x8*)xp2h;

    float den = 0.f;
    float acc[8] = {0.f,0.f,0.f,0.f,0.f,0.f,0.f,0.f};
    for (int base = jbeg; base < jend; base += 64) {
        int c = jend - base; if (c > 64) c = 64;
        int s = 0; float ex = 0.f;
        if (l < c) {
            s = csr_src[base + l];
            float e = ssrc[s] + sd;
            e = e > 0.f ? e : 0.2f * e;
            ex = __expf(e);
        }
        den += ex;
        int i = 0;
        for (; 8 * (i + 1) < c; i += 2) {
            int ea = 8 * i + grp, eb = 8 * i + 8 + grp;
            int   sa = __shfl(s, ea),  sb = __shfl(s, eb);
            float aa = __shfl(ex, ea), ab = __shfl(ex, eb);
            f16x8 va = xv[sa * 8 + sub];
            f16x8 vb = xv[sb * 8 + sub];
#pragma unroll
            for (int j = 0; j < 8; ++j) acc[j] = fmaf(aa, (float)va[j], acc[j]);
#pragma unroll
            for (int j = 0; j < 8; ++j) acc[j] = fmaf(ab, (float)vb[j], acc[j]);
        }
        for (; 8 * i < c; ++i) {
            int eidx = 8 * i + grp;
            int   se = __shfl(s, eidx);
            float ae = __shfl(ex, eidx);
            f16x8 v = xv[se * 8 + sub];
#pragma unroll
            for (int j = 0; j < 8; ++j) acc[j] = fmaf(ae, (float)v[j], acc[j]);
        }
    }
#pragma unroll
    for (int off = 32; off; off >>= 1) den += __shfl_xor(den, off);
    const float rd = 1.f / (den + 1e-16f);
#pragma unroll
    for (int j = 0; j < 8; ++j) {
        acc[j] += __shfl_xor(acc[j], 8);
        acc[j] += __shfl_xor(acc[j], 16);
        acc[j] += __shfl_xor(acc[j], 32);
    }
    if (grp == 0) {
        const float4* b4 = (const float4*)bias;
        float4 ba = b4[sub * 2], bb = b4[sub * 2 + 1];
        float4 o0, o1;
        o0.x = fmaf(acc[0], rd, ba.x); o0.y = fmaf(acc[1], rd, ba.y);
        o0.z = fmaf(acc[2], rd, ba.z); o0.w = fmaf(acc[3], rd, ba.w);
        o1.x = fmaf(acc[4], rd, bb.x); o1.y = fmaf(acc[5], rd, bb.y);
        o1.z = fmaf(acc[6], rd, bb.z); o1.w = fmaf(acc[7], rd, bb.w);
        float4* ov = (float4*)out + n * 16 + sub * 2;
        ov[0] = o0; ov[1] = o1;
    }
}

extern "C" void kernel_launch(void* const* d_in, const int* in_sizes, int n_in,
                              void* d_out, int out_size, void* d_ws, size_t ws_size,
                              hipStream_t stream)
{
    (void)in_sizes; (void)n_in; (void)out_size; (void)ws_size;
    const float* x   = (const float*)d_in[0];
    const int*   ei  = (const int*)d_in[1];
    const float* W1  = (const float*)d_in[2];
    const float* as1 = (const float*)d_in[3];
    const float* ad1 = (const float*)d_in[4];
    const float* b1  = (const float*)d_in[5];
    const float* W2  = (const float*)d_in[6];
    const float* as2 = (const float*)d_in[7];
    const float* ad2 = (const float*)d_in[8];
    const float* b2  = (const float*)d_in[9];
    float* out = (float*)d_out;

    // workspace layout (~61 MB)
    f16* xp1h    = (f16*)d_ws;                             // N*256 f16 (25.6 MB)
    f16* hbuf    = xp1h + (size_t)NODES * F1;              // N*256 f16 (25.6 MB)
    f16* W1p     = hbuf + (size_t)NODES * F1;              // 32768 f16
    f16* W2p     = W1p + 32768;                            // 16384 f16
    float* ssrc1 = (float*)(W2p + 16384);                  // N*4
    float* sdst1 = ssrc1 + (size_t)NODES * HEADS;          // N*4
    float* ssrc2 = sdst1 + (size_t)NODES * HEADS;          // N
    float* sdst2 = ssrc2 + (size_t)NODES;                  // N
    int* row_ptr = (int*)(sdst2 + (size_t)NODES);          // N+1
    int* blkhist = row_ptr + NODES + 1;                    // NB*PB = 38416
    int* rowtot  = blkhist + NB * PB;                      // NB
    int* csr_src = rowtot + NB;                            // NE2
    unsigned* staged = (unsigned*)(csr_src + NE2);         // NEDGE (3.2 MB)
    f16* xp2h    = xp1h;   // alias: xp1h dead after k_agg1

    // ---- CSR build: bucketed counting sort, zero global atomics ----
    k_hist<<<PB + 192, 256, 0, stream>>>(ei, blkhist, W1, W2, W1p, W2p);
    k_scanR<<<NB, 256, 0, stream>>>(blkhist, rowtot);
    k_part<<<PB, 256, 0, stream>>>(ei, blkhist, rowtot, staged);

    // ---- fused: bucket CSR-finish (src-sorted) || layer-1 GEMM ----
    k_bg<<<NB + G1B, 256, 0, stream>>>(staged, rowtot, row_ptr, csr_src,
                                       x, W1p, as1, ad1, xp1h, ssrc1, sdst1);

    // ---- layer 1 aggregate ----
    k_agg1<<<NODES / 4, 256, 0, stream>>>(row_ptr, csr_src, ssrc1, sdst1,
                                          xp1h, b1, hbuf);

    // ---- layer 2 ----
    k_gemm2m<<<(MTILES + 3) / 4, 256, 0, stream>>>(hbuf, W2p, as2, ad2,
                                                   xp2h, ssrc2, sdst2);
    k_agg2<<<NODES / 4, 256, 0, stream>>>(row_ptr, csr_src, ssrc2, sdst2,
                                          xp2h, b2, out);
}

// Round 5
// 227.368 us; speedup vs baseline: 1.3849x; 1.0046x over previous
//
#include <hip/hip_runtime.h>
#include <hip/hip_bf16.h>
#include <hip/hip_fp16.h>

// Problem constants (from reference)
#define NODES 50000
#define NEDGE 800000
#define NE2   850000   // NEDGE + NODES self-loops
#define INDIM 128
#define F1    256      // HEADS*HID
#define HEADS 4
#define HID   64
#define OUTD  64
#define MTILES 3125    // NODES/16

// Bucketed CSR build (no global atomics)
#define NB   196       // buckets = ceil(NODES/256); bucket q covers nodes [q*256, ...)
#define PB   196       // partition blocks
#define EPB  4096      // edges per partition block (196*4096 = 802816 >= NEDGE)
#define CAP  6144      // per-bucket LDS sort capacity (mean 4082, sigma 64 -> safe)
#define G1B  782       // ceil(MTILES/4) gemm1 blocks in fused k_bg

typedef _Float16 f16;
typedef _Float16 f16x8 __attribute__((ext_vector_type(8)));
typedef float    f32x4 __attribute__((ext_vector_type(4)));

// ===== CSR pass 1: per-block LDS bucket histogram (+ W pre-swizzle blocks) ==
__global__ void k_hist(const int* __restrict__ ei, int* __restrict__ blkhist,
                       const float* __restrict__ W1, const float* __restrict__ W2,
                       f16* __restrict__ W1p, f16* __restrict__ W2p)
{
    const int b = blockIdx.x, t = threadIdx.x;
    if (b < PB) {
        __shared__ int h[NB];
        for (int i = t; i < NB; i += 256) h[i] = 0;
        __syncthreads();
        const int e0 = b * EPB;
        const int eend = min(e0 + EPB, NEDGE);
        for (int i = e0 + t; i < eend; i += 256) {
            int d = ei[NEDGE + i];
            atomicAdd(&h[d >> 8], 1);
        }
        __syncthreads();
        // row-major [bucket][block] layout
        for (int i = t; i < NB; i += 256) blkhist[i * PB + b] = h[i];
    } else {
        int idx = (b - PB) * 256 + t;     // < 49152
        if (idx < 32768) {
            int j = idx & 7, l = (idx >> 3) & 63, fi = idx >> 9;
            int kb = fi & 3, ct = fi >> 2;
            int k = kb * 32 + (l >> 4) * 8 + j;
            int col = ct * 16 + (l & 15);
            W1p[idx] = (f16)W1[k * F1 + col];
        } else {
            int i2 = idx - 32768;         // < 16384
            int j = i2 & 7, l = (i2 >> 3) & 63, fi = i2 >> 9;
            int kb = fi & 7, ct = fi >> 3;
            int k = kb * 32 + (l >> 4) * 8 + j;
            int col = ct * 16 + (l & 15);
            W2p[i2] = (f16)W2[k * OUTD + col];
        }
    }
}

// ===== CSR pass 2: per-row exclusive scan (196 entries/row, 1 block/row) ====
__global__ void k_scanR(int* __restrict__ blkhist, int* __restrict__ rowtot)
{
    __shared__ int sh[256];
    const int q = blockIdx.x, t = threadIdx.x;
    int v = (t < PB) ? blkhist[q * PB + t] : 0;
    sh[t] = v; __syncthreads();
    for (int off = 1; off < 256; off <<= 1) {
        int tv = (t >= off) ? sh[t - off] : 0;
        __syncthreads();
        sh[t] += tv;
        __syncthreads();
    }
    if (t < PB) blkhist[q * PB + t] = sh[t] - v;
    if (t == 255) rowtot[q] = sh[255];
}

// ===== CSR pass 3: deterministic partition into bucket-ordered staging ======
__global__ void k_part(const int* __restrict__ ei, const int* __restrict__ blkhist,
                       const int* __restrict__ rowtot, unsigned* __restrict__ staged)
{
    const int b = blockIdx.x, t = threadIdx.x;
    __shared__ int sS[256];
    __shared__ int cur[NB];
    int v = (t < NB) ? rowtot[t] : 0;
    sS[t] = v; __syncthreads();
    for (int off = 1; off < 256; off <<= 1) {
        int tv = (t >= off) ? sS[t - off] : 0;
        __syncthreads();
        sS[t] += tv;
        __syncthreads();
    }
    if (t < NB) cur[t] = (sS[t] - v) + blkhist[t * PB + b];  // S[q] + rowexcl
    __syncthreads();
    const int e0 = b * EPB;
    const int eend = min(e0 + EPB, NEDGE);
    for (int i = e0 + t; i < eend; i += 256) {
        int sN = ei[i];
        int d  = ei[NEDGE + i];
        int pos = atomicAdd(&cur[d >> 8], 1);       // LDS atomic
        staged[pos] = (unsigned)sN | ((unsigned)(d & 255) << 16);
    }
}

// ===== FUSED pass 4 + layer-1 GEMM =========================================
__global__ __launch_bounds__(256) void k_bg(
    const unsigned* __restrict__ staged, const int* __restrict__ rowtot,
    int* __restrict__ row_ptr, int* __restrict__ csr_src,
    const float* __restrict__ x, const f16* __restrict__ W1p,
    const float* __restrict__ as1, const float* __restrict__ ad1,
    f16* __restrict__ xp1h, float* __restrict__ ssrc, float* __restrict__ sdst)
{
    if (blockIdx.x < NB) {
        __shared__ unsigned sorted2[CAP];   // 24 KB
        __shared__ int bin[256];
        __shared__ int cnt[256];
        __shared__ int sh[256];
        __shared__ int ssum[4];
        const int q = blockIdx.x, t = threadIdx.x;
        const int wv = t >> 6, lane = t & 63;
        int pv = (t < q) ? rowtot[t] : 0;
#pragma unroll
        for (int off = 32; off; off >>= 1) pv += __shfl_xor(pv, off);
        if (lane == 0) ssum[wv] = pv;
        cnt[t] = 0; bin[t] = 0;
        __syncthreads();
        const int estart = ssum[0] + ssum[1] + ssum[2] + ssum[3];
        const int m = rowtot[q];            // bucket edge count
        const int nodebase = q * 256;
        const int nn = min(256, NODES - nodebase);
        const int csrbase = estart + nodebase;

        const bool dosort = (m <= CAP);
        if (dosort) {
            for (int i = t; i < m; i += 256)
                atomicAdd(&bin[(staged[estart + i] & 0xFFFFu) >> 8], 1);
            __syncthreads();
            int bv = bin[t];
            sh[t] = bv;
            __syncthreads();
            for (int off = 1; off < 256; off <<= 1) {
                int tv = (t >= off) ? sh[t - off] : 0;
                __syncthreads();
                sh[t] += tv;
                __syncthreads();
            }
            bin[t] = sh[t] - bv;
            __syncthreads();
            for (int i = t; i < m; i += 256) {
                unsigned u = staged[estart + i];
                int p = atomicAdd(&bin[(u & 0xFFFFu) >> 8], 1);
                sorted2[p] = u;
            }
            __syncthreads();
        }

        if (dosort) {
            for (int i = t; i < m; i += 256)
                atomicAdd(&cnt[sorted2[i] >> 16], 1);
        } else {
            for (int i = t; i < m; i += 256)
                atomicAdd(&cnt[staged[estart + i] >> 16], 1);
        }
        __syncthreads();
        int v = cnt[t];
        sh[t] = v;
        __syncthreads();
        for (int off = 1; off < 256; off <<= 1) {
            int tv = (t >= off) ? sh[t - off] : 0;
            __syncthreads();
            sh[t] += tv;
            __syncthreads();
        }
        int excl = sh[t] - v;
        __syncthreads();
        if (t < nn) {
            int r = csrbase + excl + t;
            row_ptr[nodebase + t] = r;
            csr_src[r] = nodebase + t;      // self-loop in slot 0
            cnt[t] = excl + t + 1;
        }
        __syncthreads();
        if (dosort) {
            for (int i = t; i < m; i += 256) {
                unsigned u = sorted2[i];
                int pos = atomicAdd(&cnt[u >> 16], 1);
                csr_src[csrbase + pos] = (int)(u & 0xFFFFu);
            }
        } else {
            for (int i = t; i < m; i += 256) {
                unsigned u = staged[estart + i];
                int pos = atomicAdd(&cnt[u >> 16], 1);
                csr_src[csrbase + pos] = (int)(u & 0xFFFFu);
            }
        }
        if (q == NB - 1 && t == 0) row_ptr[NODES] = NE2;
        return;
    }

    // ---- gemm1 path ----
    const int wv = threadIdx.x >> 6, lane = threadIdx.x & 63;
    const int l15 = lane & 15, quad = lane >> 4;
    const int rowtile = (blockIdx.x - NB) * 4 + wv;
    if (rowtile >= MTILES) return;
    const int rowbase = rowtile * 16;

    f16x8 afrag[4];
    const float* xrow = x + (rowbase + l15) * INDIM + quad * 8;
#pragma unroll
    for (int kb = 0; kb < 4; ++kb) {
        float4 u0 = *(const float4*)(xrow + kb * 32);
        float4 u1 = *(const float4*)(xrow + kb * 32 + 4);
        f16x8 a;
        a[0] = (f16)u0.x; a[1] = (f16)u0.y; a[2] = (f16)u0.z; a[3] = (f16)u0.w;
        a[4] = (f16)u1.x; a[5] = (f16)u1.y; a[6] = (f16)u1.z; a[7] = (f16)u1.w;
        afrag[kb] = a;
    }

    const f16x8* Wf = (const f16x8*)W1p;
    f32x4 acc[16];
#pragma unroll
    for (int ct = 0; ct < 16; ++ct) acc[ct] = (f32x4){0.f, 0.f, 0.f, 0.f};
#pragma unroll
    for (int ct = 0; ct < 16; ++ct) {
#pragma unroll
        for (int kb = 0; kb < 4; ++kb) {
            f16x8 b = Wf[(ct * 4 + kb) * 64 + lane];
            acc[ct] = __builtin_amdgcn_mfma_f32_16x16x32_f16(afrag[kb], b, acc[ct], 0, 0, 0);
        }
    }
    const int orow = rowbase + quad * 4;
#pragma unroll
    for (int ct = 0; ct < 16; ++ct) {
#pragma unroll
        for (int r = 0; r < 4; ++r)
            xp1h[(orow + r) * F1 + ct * 16 + l15] = (f16)acc[ct][r];
    }
    float ps[4][4], pd[4][4];
#pragma unroll
    for (int h = 0; h < 4; ++h)
#pragma unroll
        for (int r = 0; r < 4; ++r) { ps[h][r] = 0.f; pd[h][r] = 0.f; }
#pragma unroll
    for (int ct = 0; ct < 16; ++ct) {
        float av = as1[ct * 16 + l15];
        float dv = ad1[ct * 16 + l15];
        int h = ct >> 2;
#pragma unroll
        for (int r = 0; r < 4; ++r) {
            ps[h][r] = fmaf(acc[ct][r], av, ps[h][r]);
            pd[h][r] = fmaf(acc[ct][r], dv, pd[h][r]);
        }
    }
#pragma unroll
    for (int off = 8; off; off >>= 1) {
#pragma unroll
        for (int h = 0; h < 4; ++h)
#pragma unroll
            for (int r = 0; r < 4; ++r) {
                ps[h][r] += __shfl_xor(ps[h][r], off);
                pd[h][r] += __shfl_xor(pd[h][r], off);
            }
    }
    if (l15 == 0) {
#pragma unroll
        for (int r = 0; r < 4; ++r) {
            int row = orow + r;
            float4 vs = {ps[0][r], ps[1][r], ps[2][r], ps[3][r]};
            float4 vd = {pd[0][r], pd[1][r], pd[2][r], pd[3][r]};
            ((float4*)ssrc)[row] = vs;
            ((float4*)sdst)[row] = vd;
        }
    }
}

// ===== Layer 1 softmax+aggregate FUSED with layer-2 GEMM ===================
// 512 threads = 8 waves = 8 nodes. Each wave: unchanged per-node aggregation,
// output row (relu+bias, f16) -> LDS tile [16][256] (rows 8..15 zero).
// Then wave 0 runs the (verified) gemm2m MFMA tile from LDS and writes
// xp2h + layer-2 scores. Deletes k_gemm2m and the 51 MB hbuf round-trip.
__global__ __launch_bounds__(512) void k_agg1f(
    const int* __restrict__ row_ptr, const int* __restrict__ csr_src,
    const float* __restrict__ ssrc, const float* __restrict__ sdst,
    const f16* __restrict__ xp1h, const float* __restrict__ bias,
    const f16* __restrict__ W2p, const float* __restrict__ as2,
    const float* __restrict__ ad2,
    f16* __restrict__ xp2h, float* __restrict__ ssrc2, float* __restrict__ sdst2)
{
    __shared__ f16 hl[16][256];                 // 8 KB
    f16x8* hu = (f16x8*)&hl[0][0];              // 512 units of 8 f16
    const int t = threadIdx.x;
    if (t < 256) hu[256 + t] = (f16x8){0,0,0,0,0,0,0,0};   // zero rows 8..15

    const int wv = t >> 6, l = t & 63;
    const int n = blockIdx.x * 8 + wv;
    const int eq = l & 15, ph = l >> 4;        // phase-A role
    const int g  = l >> 4, sub = l & 15;       // phase-B role
    const int sel_lo = (sub >> 3) << 4;        // head of unit sub (0/1) -> lane blk
    const int sel_hi = (2 + (sub >> 3)) << 4;  // head of unit sub+16 (2/3)
    const float sd = sdst[n * HEADS + ph];
    const int jbeg = row_ptr[n], jend = row_ptr[n + 1];
    const f16x8* xv = (const f16x8*)xp1h;

    float den = 0.f;
    float alo[8] = {0.f,0.f,0.f,0.f,0.f,0.f,0.f,0.f};
    float ahi[8] = {0.f,0.f,0.f,0.f,0.f,0.f,0.f,0.f};
    for (int base = jbeg; base < jend; base += 16) {
        int c = jend - base; if (c > 16) c = 16;
        int s = 0; float ex = 0.f;
        if (eq < c) {
            s = csr_src[base + eq];
            float e = ssrc[s * HEADS + ph] + sd;
            e = e > 0.f ? e : 0.2f * e;
            ex = __expf(e);
        }
        den += ex;
        int p = 0;
        for (; p + 7 < c; p += 8) {            // 8 edges in flight
            int ea = p + g, eb = p + 4 + g;
            int   sa  = __shfl(s, ea),          sb  = __shfl(s, eb);
            float aal = __shfl(ex, ea | sel_lo), aah = __shfl(ex, ea | sel_hi);
            float abl = __shfl(ex, eb | sel_lo), abh = __shfl(ex, eb | sel_hi);
            f16x8 va0 = xv[sa * 32 + sub];
            f16x8 va1 = xv[sa * 32 + sub + 16];
            f16x8 vb0 = xv[sb * 32 + sub];
            f16x8 vb1 = xv[sb * 32 + sub + 16];
#pragma unroll
            for (int j = 0; j < 8; ++j) {
                alo[j] = fmaf(aal, (float)va0[j], alo[j]);
                ahi[j] = fmaf(aah, (float)va1[j], ahi[j]);
            }
#pragma unroll
            for (int j = 0; j < 8; ++j) {
                alo[j] = fmaf(abl, (float)vb0[j], alo[j]);
                ahi[j] = fmaf(abh, (float)vb1[j], ahi[j]);
            }
        }
        for (; p < c; p += 4) {                // 4 edges, ex=0 pads
            int ea = p + g;
            int   sa  = __shfl(s, ea);
            float aal = __shfl(ex, ea | sel_lo), aah = __shfl(ex, ea | sel_hi);
            f16x8 va0 = xv[sa * 32 + sub];
            f16x8 va1 = xv[sa * 32 + sub + 16];
#pragma unroll
            for (int j = 0; j < 8; ++j) {
                alo[j] = fmaf(aal, (float)va0[j], alo[j]);
                ahi[j] = fmaf(aah, (float)va1[j], ahi[j]);
            }
        }
    }
#pragma unroll
    for (int off = 8; off; off >>= 1) den += __shfl_xor(den, off);
    const float dl = __shfl(den, sel_lo);
    const float dh = __shfl(den, sel_hi);
    const float rdl = 1.f / (dl + 1e-16f);
    const float rdh = 1.f / (dh + 1e-16f);
#pragma unroll
    for (int j = 0; j < 8; ++j) {
        alo[j] += __shfl_xor(alo[j], 16); alo[j] += __shfl_xor(alo[j], 32);
        ahi[j] += __shfl_xor(ahi[j], 16); ahi[j] += __shfl_xor(ahi[j], 32);
    }
    if (g == 0) {
        const float4* b4 = (const float4*)bias;
        float4 bl0 = b4[sub * 2],        bl1 = b4[sub * 2 + 1];
        float4 bh0 = b4[(sub + 16) * 2], bh1 = b4[(sub + 16) * 2 + 1];
        f16x8 olo, ohi;
        float v;
        v = fmaf(alo[0], rdl, bl0.x); olo[0] = (f16)(v > 0.f ? v : 0.f);
        v = fmaf(alo[1], rdl, bl0.y); olo[1] = (f16)(v > 0.f ? v : 0.f);
        v = fmaf(alo[2], rdl, bl0.z); olo[2] = (f16)(v > 0.f ? v : 0.f);
        v = fmaf(alo[3], rdl, bl0.w); olo[3] = (f16)(v > 0.f ? v : 0.f);
        v = fmaf(alo[4], rdl, bl1.x); olo[4] = (f16)(v > 0.f ? v : 0.f);
        v = fmaf(alo[5], rdl, bl1.y); olo[5] = (f16)(v > 0.f ? v : 0.f);
        v = fmaf(alo[6], rdl, bl1.z); olo[6] = (f16)(v > 0.f ? v : 0.f);
        v = fmaf(alo[7], rdl, bl1.w); olo[7] = (f16)(v > 0.f ? v : 0.f);
        v = fmaf(ahi[0], rdh, bh0.x); ohi[0] = (f16)(v > 0.f ? v : 0.f);
        v = fmaf(ahi[1], rdh, bh0.y); ohi[1] = (f16)(v > 0.f ? v : 0.f);
        v = fmaf(ahi[2], rdh, bh0.z); ohi[2] = (f16)(v > 0.f ? v : 0.f);
        v = fmaf(ahi[3], rdh, bh0.w); ohi[3] = (f16)(v > 0.f ? v : 0.f);
        v = fmaf(ahi[4], rdh, bh1.x); ohi[4] = (f16)(v > 0.f ? v : 0.f);
        v = fmaf(ahi[5], rdh, bh1.y); ohi[5] = (f16)(v > 0.f ? v : 0.f);
        v = fmaf(ahi[6], rdh, bh1.z); ohi[6] = (f16)(v > 0.f ? v : 0.f);
        v = fmaf(ahi[7], rdh, bh1.w); ohi[7] = (f16)(v > 0.f ? v : 0.f);
        hu[wv * 32 + sub]      = olo;          // LDS, not global
        hu[wv * 32 + sub + 16] = ohi;
    }
    __syncthreads();

    // ---- wave 0: layer-2 GEMM tile (16 rows: 8 real + 8 zero) ----
    if (wv == 0) {
        const int lane = l;
        const int l15 = lane & 15, quad = lane >> 4;
        const f16x8* Wf = (const f16x8*)W2p;
        f32x4 acc2[4];
#pragma unroll
        for (int ct = 0; ct < 4; ++ct) acc2[ct] = (f32x4){0.f, 0.f, 0.f, 0.f};
#pragma unroll
        for (int kb = 0; kb < 8; ++kb) {
            f16x8 a = hu[l15 * 32 + quad + kb * 4];   // row l15, ch quad*8+kb*32
#pragma unroll
            for (int ct = 0; ct < 4; ++ct) {
                f16x8 b = Wf[(ct * 8 + kb) * 64 + lane];
                acc2[ct] = __builtin_amdgcn_mfma_f32_16x16x32_f16(a, b, acc2[ct], 0, 0, 0);
            }
        }
        const int rowbase = blockIdx.x * 8;
#pragma unroll
        for (int ct = 0; ct < 4; ++ct) {
#pragma unroll
            for (int r = 0; r < 4; ++r) {
                int row = quad * 4 + r;
                if (row < 8)
                    xp2h[(rowbase + row) * OUTD + ct * 16 + l15] = (f16)acc2[ct][r];
            }
        }
        float ps[4] = {0.f,0.f,0.f,0.f}, pd[4] = {0.f,0.f,0.f,0.f};
#pragma unroll
        for (int ct = 0; ct < 4; ++ct) {
            float av = as2[ct * 16 + l15];
            float dv = ad2[ct * 16 + l15];
#pragma unroll
            for (int r = 0; r < 4; ++r) {
                ps[r] = fmaf(acc2[ct][r], av, ps[r]);
                pd[r] = fmaf(acc2[ct][r], dv, pd[r]);
            }
        }
#pragma unroll
        for (int off = 8; off; off >>= 1) {
#pragma unroll
            for (int r = 0; r < 4; ++r) {
                ps[r] += __shfl_xor(ps[r], off);
                pd[r] += __shfl_xor(pd[r], off);
            }
        }
        if (l15 == 0) {
#pragma unroll
            for (int r = 0; r < 4; ++r) {
                int row = quad * 4 + r;
                if (row < 8) {
                    ssrc2[rowbase + row] = ps[r];
                    sdst2[rowbase + row] = pd[r];
                }
            }
        }
    }
}

// ===== Layer 2 fused softmax+aggregate+bias -> d_out: b128 gather =====
__global__ __launch_bounds__(256) void k_agg2(
    const int* __restrict__ row_ptr, const int* __restrict__ csr_src,
    const float* __restrict__ ssrc, const float* __restrict__ sdst,
    const f16* __restrict__ xp2h, const float* __restrict__ bias,
    float* __restrict__ out)
{
    const int wv = threadIdx.x >> 6, l = threadIdx.x & 63;
    const int n = blockIdx.x * 4 + wv;
    const int grp = l >> 3, sub = l & 7;
    const float sd = sdst[n];
    const int jbeg = row_ptr[n], jend = row_ptr[n + 1];
    const f16x8* xv = (const f16x8*)xp2h;

    float den = 0.f;
    float acc[8] = {0.f,0.f,0.f,0.f,0.f,0.f,0.f,0.f};
    for (int base = jbeg; base < jend; base += 64) {
        int c = jend - base; if (c > 64) c = 64;
        int s = 0; float ex = 0.f;
        if (l < c) {
            s = csr_src[base + l];
            float e = ssrc[s] + sd;
            e = e > 0.f ? e : 0.2f * e;
            ex = __expf(e);
        }
        den += ex;
        int i = 0;
        for (; 8 * (i + 1) < c; i += 2) {
            int ea = 8 * i + grp, eb = 8 * i + 8 + grp;
            int   sa = __shfl(s, ea),  sb = __shfl(s, eb);
            float aa = __shfl(ex, ea), ab = __shfl(ex, eb);
            f16x8 va = xv[sa * 8 + sub];
            f16x8 vb = xv[sb * 8 + sub];
#pragma unroll
            for (int j = 0; j < 8; ++j) acc[j] = fmaf(aa, (float)va[j], acc[j]);
#pragma unroll
            for (int j = 0; j < 8; ++j) acc[j] = fmaf(ab, (float)vb[j], acc[j]);
        }
        for (; 8 * i < c; ++i) {
            int eidx = 8 * i + grp;
            int   se = __shfl(s, eidx);
            float ae = __shfl(ex, eidx);
            f16x8 v = xv[se * 8 + sub];
#pragma unroll
            for (int j = 0; j < 8; ++j) acc[j] = fmaf(ae, (float)v[j], acc[j]);
        }
    }
#pragma unroll
    for (int off = 32; off; off >>= 1) den += __shfl_xor(den, off);
    const float rd = 1.f / (den + 1e-16f);
#pragma unroll
    for (int j = 0; j < 8; ++j) {
        acc[j] += __shfl_xor(acc[j], 8);
        acc[j] += __shfl_xor(acc[j], 16);
        acc[j] += __shfl_xor(acc[j], 32);
    }
    if (grp == 0) {
        const float4* b4 = (const float4*)bias;
        float4 ba = b4[sub * 2], bb = b4[sub * 2 + 1];
        float4 o0, o1;
        o0.x = fmaf(acc[0], rd, ba.x); o0.y = fmaf(acc[1], rd, ba.y);
        o0.z = fmaf(acc[2], rd, ba.z); o0.w = fmaf(acc[3], rd, ba.w);
        o1.x = fmaf(acc[4], rd, bb.x); o1.y = fmaf(acc[5], rd, bb.y);
        o1.z = fmaf(acc[6], rd, bb.z); o1.w = fmaf(acc[7], rd, bb.w);
        float4* ov = (float4*)out + n * 16 + sub * 2;
        ov[0] = o0; ov[1] = o1;
    }
}

extern "C" void kernel_launch(void* const* d_in, const int* in_sizes, int n_in,
                              void* d_out, int out_size, void* d_ws, size_t ws_size,
                              hipStream_t stream)
{
    (void)in_sizes; (void)n_in; (void)out_size; (void)ws_size;
    const float* x   = (const float*)d_in[0];
    const int*   ei  = (const int*)d_in[1];
    const float* W1  = (const float*)d_in[2];
    const float* as1 = (const float*)d_in[3];
    const float* ad1 = (const float*)d_in[4];
    const float* b1  = (const float*)d_in[5];
    const float* W2  = (const float*)d_in[6];
    const float* as2 = (const float*)d_in[7];
    const float* ad2 = (const float*)d_in[8];
    const float* b2  = (const float*)d_in[9];
    float* out = (float*)d_out;

    // workspace layout (~40 MB). NOTE: xp2h no longer aliases xp1h --
    // k_agg1f reads xp1h while writing xp2h.
    f16* xp1h    = (f16*)d_ws;                             // N*256 f16 (25.6 MB)
    f16* xp2h    = xp1h + (size_t)NODES * F1;              // N*64 f16 (6.4 MB)
    f16* W1p     = xp2h + (size_t)NODES * OUTD;            // 32768 f16
    f16* W2p     = W1p + 32768;                            // 16384 f16
    float* ssrc1 = (float*)(W2p + 16384);                  // N*4
    float* sdst1 = ssrc1 + (size_t)NODES * HEADS;          // N*4
    float* ssrc2 = sdst1 + (size_t)NODES * HEADS;          // N
    float* sdst2 = ssrc2 + (size_t)NODES;                  // N
    int* row_ptr = (int*)(sdst2 + (size_t)NODES);          // N+1
    int* blkhist = row_ptr + NODES + 1;                    // NB*PB = 38416
    int* rowtot  = blkhist + NB * PB;                      // NB
    int* csr_src = rowtot + NB;                            // NE2
    unsigned* staged = (unsigned*)(csr_src + NE2);         // NEDGE (3.2 MB)

    // ---- CSR build: bucketed counting sort, zero global atomics ----
    k_hist<<<PB + 192, 256, 0, stream>>>(ei, blkhist, W1, W2, W1p, W2p);
    k_scanR<<<NB, 256, 0, stream>>>(blkhist, rowtot);
    k_part<<<PB, 256, 0, stream>>>(ei, blkhist, rowtot, staged);

    // ---- fused: bucket CSR-finish || layer-1 GEMM ----
    k_bg<<<NB + G1B, 256, 0, stream>>>(staged, rowtot, row_ptr, csr_src,
                                       x, W1p, as1, ad1, xp1h, ssrc1, sdst1);

    // ---- layer 1 aggregate + layer 2 GEMM (fused) ----
    k_agg1f<<<NODES / 8, 512, 0, stream>>>(row_ptr, csr_src, ssrc1, sdst1,
                                           xp1h, b1, W2p, as2, ad2,
                                           xp2h, ssrc2, sdst2);

    // ---- layer 2 aggregate ----
    k_agg2<<<NODES / 4, 256, 0, stream>>>(row_ptr, csr_src, ssrc2, sdst2,
                                          xp2h, b2, out);
}